// Round 12
// baseline (301.114 us; speedup 1.0000x reference)
//
#include <hip/hip_runtime.h>
#include <hip/hip_bf16.h>
#include <math.h>

// ---------------- constants ----------------
#define TB 8
#define TT 64000
#define NFRAMES 251
#define NROWS (TB*NFRAMES)      // 2008
#define GROWS 2048              // 8 * 256 radix-4 sub-rows
#define NBINS 513
#define NBPAD 576
#define NNODE 250
#define NODE_DIM 4116
#define KPAD 4128

typedef __attribute__((ext_vector_type(8))) short short8;
typedef __attribute__((ext_vector_type(4))) float floatx4;

static __device__ __forceinline__ unsigned short f2bf(float x) {
    __hip_bfloat16 h = __float2bfloat16(x);
    return *(unsigned short*)&h;
}
static __device__ __forceinline__ float bf2f(unsigned short u) {
    __hip_bfloat16 h = *(__hip_bfloat16*)&u;
    return __bfloat162float(h);
}

// ---------------- merged prep kernel: all input-only transforms in ONE launch ----------------
__global__ __launch_bounds__(256) void k_prep(
    const float* __restrict__ x, const float* __restrict__ sinc_w,
    const float* __restrict__ c2w, const float* __restrict__ g2bn,
    const float* __restrict__ c1w, const float* __restrict__ g1bn,
    const float* __restrict__ W,
    unsigned short* __restrict__ fh, unsigned short* __restrict__ fl,
    unsigned short* __restrict__ bch, unsigned short* __restrict__ bcl,
    unsigned short* __restrict__ bsh, unsigned short* __restrict__ bsl,
    unsigned short* __restrict__ wbt, unsigned short* __restrict__ Bp,
    unsigned short* __restrict__ Bc1,
    unsigned short* __restrict__ Wt, unsigned short* __restrict__ nodesb,
    unsigned short* __restrict__ h1t, unsigned short* __restrict__ h2t) {
    __shared__ unsigned short tile[64][65];
    int bi = blockIdx.x, tid = threadIdx.x;
    if (bi < 2048) {
        int idx = bi * 256 + tid;
        int row = idx >> 8, r = idx & 255;
        int b = row >> 8, j = row & 255;
        int u = j * 256 + r - 512;
        if (u < 0) u = -u;
        if (u >= TT) u = 2 * TT - 2 - u;
        float v = x[b * TT + u];
        unsigned short h = f2bf(v);
        fh[idx] = h;
        fl[idx] = f2bf(v - bf2f(h));
    } else if (bi < 2624) {
        int idx = (bi - 2048) * 256 + tid;
        int k = idx >> 8, r = idx & 255;
        float s = 0.f, c = 0.f;
        if (k < NBINS) {
            int mm = (k * r) & 1023;
            sincospif((float)mm * (1.0f / 512.0f), &s, &c);
        }
        unsigned short chv = f2bf(c), shv = f2bf(s);
        bch[idx] = chv; bcl[idx] = f2bf(c - bf2f(chv));
        bsh[idx] = shv; bsl[idx] = f2bf(s - bf2f(shv));
    } else if (bi < 3144) {
        int local = bi - 2624;
        int kt = local % 65, nt = local / 65;
        for (int idx = tid; idx < 4096; idx += 256) {
            int r = idx >> 6, c = idx & 63;
            int kp = kt * 64 + r;
            int k;
            if (kp < 20) k = kp;
            else if (kp < NODE_DIM) { int t = kp - 20; k = 20 + (t & 15) * 256 + (t >> 4); }
            else k = -1;
            float v = (k >= 0) ? W[k * 512 + nt * 64 + c] : 0.f;
            tile[r][c] = f2bf(v);
        }
        __syncthreads();
        for (int idx = tid; idx < 4096; idx += 256) {
            int nl = idx >> 6, kl = idx & 63;
            int k = kt * 64 + kl;
            if (k < KPAD)
                Wt[(size_t)(nt * 64 + nl) * KPAD + k] = tile[kl][nl];
        }
    } else if (bi < 3276) {
        int idx = (bi - 3144) * 256 + tid;
        if (idx < 32 * 1056) {
            int c = idx / 1056, m = idx - c * 1056;
            float s = 0.f;
            if (c < 20 && m < 1027) {
                #pragma unroll
                for (int d = 0; d < 4; d++) {
                    int k = m - d;
                    if (k >= 0 && k < 1024) s += sinc_w[c * 1024 + k];
                }
                s *= 0.25f;
            }
            wbt[idx] = f2bf(s);
        }
    } else if (bi < 3312) {
        int idx = (bi - 3276) * 256 + tid;
        if (idx < 9216) {
            int j = idx & 7, lane = (idx >> 3) & 63, ct = (idx >> 9) & 1, s = idx >> 10;
            int co = ct * 16 + (lane & 15);
            int ci = (lane >> 4) * 8 + j;
            float inv = rsqrtf(1.0f + 1e-5f);
            Bp[idx] = f2bf(c2w[co * 288 + ci * 9 + s] * (g2bn[co] * inv));
        }
    } else if (bi < 3508) {
        int idx = (bi - 3312) * 256 + tid;
        if (idx < 24000) {
            int row = idx / 12, c = idx - row * 12;
            nodesb[(size_t)row * KPAD + 4116 + c] = 0;
        } else if (idx < 48576) {
            int t = idx - 24000; int r = t / 6, c = t - r * 6;
            h1t[(size_t)r * 256 + 250 + c] = 0;
        } else if (idx < 50112) {
            int t = idx - 48576; int r = t / 6, c = t - r * 6;
            h2t[(size_t)r * 256 + 250 + c] = 0;
        }
    } else {
        // conv1 weight B-fragments: Bc1[ch=32][k=32], hi/lo 3-term layout
        int idx = (bi - 3508) * 256 + tid;
        if (idx < 1024) {
            int ch = idx >> 5, k = idx & 31;
            float inv = rsqrtf(1.0f + 1e-5f);
            int t; int typ; // 0=hi 1=lo 2=zero
            if (k < 8)       { t = k;      typ = 0; }
            else if (k < 16) { t = k - 8;  typ = 0; }
            else if (k < 24) { t = k - 16; typ = 1; }
            else if (k == 24 || k == 25) { t = 8; typ = 0; }
            else if (k == 26) { t = 8; typ = 1; }
            else { t = 0; typ = 2; }
            unsigned short outv = 0;
            if (typ != 2) {
                float wv = c1w[ch * 9 + t] * (g1bn[ch] * inv);
                unsigned short whi = f2bf(wv);
                outv = (typ == 0) ? whi : f2bf(wv - bf2f(whi));
            }
            Bc1[idx] = outv;
        }
    }
}

// ---------------- radix-4 DFT GEMM (transposed GT[bin][row] output) + sinc conv, one launch ----------------
__global__ __launch_bounds__(256) void k_dftsinc(const unsigned short* __restrict__ fh,
                                                 const unsigned short* __restrict__ fl,
                                                 const unsigned short* __restrict__ ch,
                                                 const unsigned short* __restrict__ cl,
                                                 const unsigned short* __restrict__ sh,
                                                 const unsigned short* __restrict__ sl,
                                                 float* __restrict__ GTR,
                                                 float* __restrict__ GTI,
                                                 const float* __restrict__ x,
                                                 const unsigned short* __restrict__ wbt,
                                                 unsigned short* __restrict__ nodesb) {
    __shared__ __align__(16) unsigned char smem[34048];
    int tid = threadIdx.x;
    int bi = blockIdx.x;
    if (bi >= 576) {
        // ---- sinc conv as MFMA GEMM, M-split ----
        unsigned short* xs = (unsigned short*)smem;   // 1312 ush
        int local = bi - 576;
        int ut = local & 3, b = local >> 2;
        int base = 256 * ut - 512;
        for (int i = tid; i < 1312; i += 256) {
            int g = base + i;
            float v = (g >= 0 && g < TT) ? x[b * TT + g] : 0.f;
            xs[i] = f2bf(v);
        }
        __syncthreads();
        int w = tid >> 6, lane = tid & 63;
        int q = lane >> 4, col = lane & 15;
        floatx4 acc[2];
        acc[0] = acc[1] = (floatx4){0.f, 0.f, 0.f, 0.f};
        for (int K0 = 0; K0 < 1056; K0 += 32) {
            int off = 4 * (w * 16 + col) + K0 + q * 8;
            unsigned long long lo = *(const unsigned long long*)&xs[off];
            unsigned long long hi = *(const unsigned long long*)&xs[off + 4];
            union { unsigned long long u64[2]; short8 s8; } cv;
            cv.u64[0] = lo; cv.u64[1] = hi;
            short8 af = cv.s8;
            #pragma unroll
            for (int ni = 0; ni < 2; ni++) {
                short8 bf = *(const short8*)(wbt + (size_t)(ni * 16 + col) * 1056 + K0 + q * 8);
                acc[ni] = __builtin_amdgcn_mfma_f32_16x16x32_bf16(af, bf, acc[ni], 0, 0, 0);
            }
        }
        #pragma unroll
        for (int ni = 0; ni < 2; ni++)
            #pragma unroll
            for (int rr = 0; rr < 4; rr++) {
                int u = ut * 64 + w * 16 + q * 4 + rr;
                int c = ni * 16 + col;
                if (u < NNODE && c < 20)
                    nodesb[(size_t)(b * NNODE + u) * KPAD + c] = f2bf(acc[ni][rr]);
            }
        return;
    }
    // ---- DFT part ----
    unsigned short* Ah  = (unsigned short*)smem;             // 2560 B
    unsigned short* Al  = (unsigned short*)(smem + 2560);    // 2560 B
    unsigned short* Bch = (unsigned short*)(smem + 5120);    // 5120 B
    unsigned short* Bcl = (unsigned short*)(smem + 10240);
    unsigned short* Bsh = (unsigned short*)(smem + 15360);
    unsigned short* Bsl = (unsigned short*)(smem + 20480);
    float* TR = (float*)(smem + 25600);                      // 64*33*4 = 8448 B
    int N0 = (bi % 9) * 64, M0 = (bi / 9) * 32;
    int br = tid >> 2, bc = (tid & 3) * 8;
    size_t boff = (size_t)(N0 + br) * 256 + bc;
    int ar = (tid & 127) >> 2, ac = (tid & 3) * 8;
    size_t aoff = (size_t)(M0 + ar) * 256 + ac;
    bool loA = tid < 128;
    int w = tid >> 6, lane = tid & 63;
    int q = lane >> 4, col = lane & 15;
    int mb = (w >> 1) * 16, nb = (w & 1) * 32;
    floatx4 aR[2], aI[2];
    aR[0] = aR[1] = aI[0] = aI[1] = (floatx4){0.f, 0.f, 0.f, 0.f};

    for (int K0 = 0; K0 < 256; K0 += 32) {
        if (loA) *(short8*)&Ah[ar * 40 + ac] = *(const short8*)(fh + aoff + K0);
        else     *(short8*)&Al[ar * 40 + ac] = *(const short8*)(fl + aoff + K0);
        *(short8*)&Bch[br * 40 + bc] = *(const short8*)(ch + boff + K0);
        *(short8*)&Bcl[br * 40 + bc] = *(const short8*)(cl + boff + K0);
        *(short8*)&Bsh[br * 40 + bc] = *(const short8*)(sh + boff + K0);
        *(short8*)&Bsl[br * 40 + bc] = *(const short8*)(sl + boff + K0);
        __syncthreads();
        short8 ahv = *(const short8*)&Ah[(mb + col) * 40 + q * 8];
        short8 alv = *(const short8*)&Al[(mb + col) * 40 + q * 8];
        #pragma unroll
        for (int ni = 0; ni < 2; ni++) {
            short8 chv = *(const short8*)&Bch[(nb + ni * 16 + col) * 40 + q * 8];
            short8 clv = *(const short8*)&Bcl[(nb + ni * 16 + col) * 40 + q * 8];
            short8 shv = *(const short8*)&Bsh[(nb + ni * 16 + col) * 40 + q * 8];
            short8 slv = *(const short8*)&Bsl[(nb + ni * 16 + col) * 40 + q * 8];
            aR[ni] = __builtin_amdgcn_mfma_f32_16x16x32_bf16(ahv, chv, aR[ni], 0, 0, 0);
            aR[ni] = __builtin_amdgcn_mfma_f32_16x16x32_bf16(ahv, clv, aR[ni], 0, 0, 0);
            aR[ni] = __builtin_amdgcn_mfma_f32_16x16x32_bf16(alv, chv, aR[ni], 0, 0, 0);
            aI[ni] = __builtin_amdgcn_mfma_f32_16x16x32_bf16(ahv, shv, aI[ni], 0, 0, 0);
            aI[ni] = __builtin_amdgcn_mfma_f32_16x16x32_bf16(ahv, slv, aI[ni], 0, 0, 0);
            aI[ni] = __builtin_amdgcn_mfma_f32_16x16x32_bf16(alv, shv, aI[ni], 0, 0, 0);
        }
        __syncthreads();
    }
    // transpose epilogue via LDS: coalesced GT[bin][row] writes
    int bin_l = tid >> 2, ms = (tid & 3) * 8;
    #pragma unroll
    for (int ni = 0; ni < 2; ni++)
        #pragma unroll
        for (int rr = 0; rr < 4; rr++)
            TR[(nb + ni * 16 + col) * 33 + mb + q * 4 + rr] = aR[ni][rr];
    __syncthreads();
    {
        float* dst = GTR + (size_t)(N0 + bin_l) * 2048 + M0 + ms;
        #pragma unroll
        for (int j = 0; j < 8; j++) dst[j] = TR[bin_l * 33 + ms + j];
    }
    __syncthreads();
    #pragma unroll
    for (int ni = 0; ni < 2; ni++)
        #pragma unroll
        for (int rr = 0; rr < 4; rr++)
            TR[(nb + ni * 16 + col) * 33 + mb + q * 4 + rr] = aI[ni][rr];
    __syncthreads();
    {
        float* dst = GTI + (size_t)(N0 + bin_l) * 2048 + M0 + ms;
        #pragma unroll
        for (int j = 0; j < 8; j++) dst[j] = TR[bin_l * 33 + ms + j];
    }
}

// ---------------- fused conv1+conv2; S0 tile hi/lo-precomputed in LDS ----------------
#define O1STR 40
__global__ __launch_bounds__(256) void k_conv2f(const float* __restrict__ GTR,
                                                const float* __restrict__ GTI,
                                                const unsigned short* __restrict__ Bc1,
                                                const float* __restrict__ c1b,
                                                const float* __restrict__ g1bn,
                                                const float* __restrict__ b1bn,
                                                const unsigned short* __restrict__ Bp,
                                                const float* __restrict__ c2b,
                                                const float* __restrict__ g2bn,
                                                const float* __restrict__ b2bn,
                                                unsigned short* __restrict__ nodesb) {
    __shared__ __align__(16) unsigned short o1s[18 * 18 * O1STR];  // 25920 B
    __shared__ unsigned short S0h[400];
    __shared__ unsigned short S0l[400];
    __shared__ float b1s[32];
    __shared__ float b2s[32];
    int tid = threadIdx.x;
    int b = blockIdx.z;
    int F0 = blockIdx.y * 8;
    int T0 = blockIdx.x * 8;
    float inv = rsqrtf(1.0f + 1e-5f);
    if (tid < 32) {
        b1s[tid] = c1b[tid] * (g1bn[tid] * inv) + b1bn[tid];
        b2s[tid] = c2b[tid] * (g2bn[tid] * inv) + b2bn[tid];
    }
    for (int i = tid; i < 400; i += 256) {
        int r = i / 20, c = i - r * 20;
        int bin = 2 * F0 - 2 + r, fr = 2 * T0 - 2 + c;
        float v = 0.f;
        if (bin >= 0 && bin < 513 && fr >= 0 && fr < 251) {
            size_t base = (size_t)bin * 2048 + b * 256 + fr;
            float gr0 = GTR[base], gr1 = GTR[base + 1], gr2 = GTR[base + 2], gr3 = GTR[base + 3];
            float gs0 = GTI[base], gs1 = GTI[base + 1], gs2 = GTI[base + 2], gs3 = GTI[base + 3];
            float fre, fim;
            switch (bin & 3) {
                case 0: fre = gr0 + gr1 + gr2 + gr3; fim = gs0 + gs1 + gs2 + gs3; break;
                case 1: fre = gr0 - gs1 - gr2 + gs3; fim = gs0 + gr1 - gs2 - gr3; break;
                case 2: fre = gr0 - gr1 + gr2 - gr3; fim = gs0 - gs1 + gs2 - gs3; break;
                default: fre = gr0 + gs1 - gr2 - gs3; fim = gs0 - gr1 - gs2 + gr3; break;
            }
            v = logf(sqrtf(fmaf(fre, fre, fim * fim)) + 1e-9f);
        }
        unsigned short hv = f2bf(v);
        S0h[i] = hv;
        S0l[i] = f2bf(v - bf2f(hv));
    }
    __syncthreads();

    int lane = tid & 63, w = tid >> 6;
    int q = lane >> 4, col = lane & 15;

    // ---- conv1 as MFMA: positions p = r*18+t (324), channels 32, K=32 packed hi/lo ----
    {
        short8 bfr0 = *(const short8*)(Bc1 + (size_t)col * 32 + q * 8);
        short8 bfr1 = *(const short8*)(Bc1 + (size_t)(16 + col) * 32 + q * 8);
        for (int mt = w; mt < 21; mt += 4) {
            int p = mt * 16 + col;
            int pc = p < 324 ? p : 0;
            int pr = (pc * 228) >> 12;      // pc/18
            int pt = pc - pr * 18;
            int wb = pr * 20 + pt;          // window base in S0h/S0l
            short8 af;
            if (q == 1) {
                af[0] = S0l[wb];      af[1] = S0l[wb + 1];  af[2] = S0l[wb + 2];
                af[3] = S0l[wb + 20]; af[4] = S0l[wb + 21]; af[5] = S0l[wb + 22];
                af[6] = S0l[wb + 40]; af[7] = S0l[wb + 41];
            } else if (q == 3) {
                unsigned short h8 = S0h[wb + 42];
                unsigned short l8 = S0l[wb + 42];
                af[0] = h8; af[1] = l8; af[2] = h8; af[3] = 0;
                af[4] = 0; af[5] = 0; af[6] = 0; af[7] = 0;
            } else {
                af[0] = S0h[wb];      af[1] = S0h[wb + 1];  af[2] = S0h[wb + 2];
                af[3] = S0h[wb + 20]; af[4] = S0h[wb + 21]; af[5] = S0h[wb + 22];
                af[6] = S0h[wb + 40]; af[7] = S0h[wb + 41];
            }
            floatx4 c0 = (floatx4){0.f, 0.f, 0.f, 0.f};
            floatx4 c1 = (floatx4){0.f, 0.f, 0.f, 0.f};
            c0 = __builtin_amdgcn_mfma_f32_16x16x32_bf16(af, bfr0, c0, 0, 0, 0);
            c1 = __builtin_amdgcn_mfma_f32_16x16x32_bf16(af, bfr1, c1, 0, 0, 0);
            #pragma unroll
            for (int rr2 = 0; rr2 < 4; rr2++) {
                int pp = mt * 16 + q * 4 + rr2;
                if (pp < 324) {
                    int qr = (pp * 228) >> 12, qt = pp - qr * 18;
                    int r1 = 2 * F0 - 1 + qr, t1 = 2 * T0 - 1 + qt;
                    bool valid = (r1 >= 0 && r1 < 513 && t1 >= 0 && t1 < 251);
                    float v0 = fmaxf(c0[rr2] + b1s[col], 0.f);
                    float v1 = fmaxf(c1[rr2] + b1s[16 + col], 0.f);
                    o1s[pp * O1STR + col]      = valid ? f2bf(v0) : (unsigned short)0;
                    o1s[pp * O1STR + 16 + col] = valid ? f2bf(v1) : (unsigned short)0;
                }
            }
        }
    }
    __syncthreads();

    floatx4 acc[4][2];
    #pragma unroll
    for (int rt = 0; rt < 4; rt++)
        #pragma unroll
        for (int ct = 0; ct < 2; ct++)
            acc[rt][ct] = (floatx4){0.f, 0.f, 0.f, 0.f};

    #pragma unroll
    for (int s = 0; s < 9; s++) {
        const int di = s / 3, dj = s % 3;
        short8 bf0 = *(const short8*)&Bp[(s * 2 + 0) * 512 + lane * 8];
        short8 bf1 = *(const short8*)&Bp[(s * 2 + 1) * 512 + lane * 8];
        #pragma unroll
        for (int rt = 0; rt < 4; rt++) {
            short8 af = *(const short8*)&o1s[((w * 4 + rt + di) * 18 + (col + dj)) * O1STR + q * 8];
            acc[rt][0] = __builtin_amdgcn_mfma_f32_16x16x32_bf16(af, bf0, acc[rt][0], 0, 0, 0);
            acc[rt][1] = __builtin_amdgcn_mfma_f32_16x16x32_bf16(af, bf1, acc[rt][1], 0, 0, 0);
        }
    }
    __syncthreads();

    unsigned short* nb = o1s;
    #pragma unroll
    for (int ct = 0; ct < 2; ct++) {
        float bb = b2s[ct * 16 + col];
        #pragma unroll
        for (int fp2 = 0; fp2 < 2; fp2++)
            #pragma unroll
            for (int tc2 = 0; tc2 < 2; tc2++) {
                float m0 = fmaxf(
                    fmaxf(acc[2 * fp2][ct][2 * tc2], acc[2 * fp2][ct][2 * tc2 + 1]),
                    fmaxf(acc[2 * fp2 + 1][ct][2 * tc2], acc[2 * fp2 + 1][ct][2 * tc2 + 1]));
                float v = fmaxf(m0 + bb, 0.f);
                int nl = (2 * q + tc2) * 2 + ct;   // 0..15
                int fl = 2 * w + fp2;              // 0..7
                nb[nl * 136 + fl * 16 + col] = f2bf(v);
            }
    }
    __syncthreads();

    int nl = tid >> 4, part = tid & 15;
    int node_g = 2 * T0 + nl;
    if (node_g < NNODE) {
        unsigned short* dst = nodesb + (size_t)(b * NNODE + node_g) * KPAD + 20 + F0 * 16 + part * 8;
        *(short8*)(dst) = *(const short8*)&nb[nl * 136 + part * 8];
    }
}

// ---------------- GAT1 GEMM split-K (bf16 MFMA): hpart[kc][2000][512] ----------------
__global__ __launch_bounds__(256) void k_gat1s(const unsigned short* __restrict__ A,
                                               const unsigned short* __restrict__ Bt,
                                               float* __restrict__ hpart) {
    __shared__ __align__(16) unsigned short As[64 * 40];
    __shared__ __align__(16) unsigned short Bs[64 * 40];
    int tid = threadIdx.x;
    int N0 = blockIdx.x * 64, M0 = blockIdx.y * 64;
    int kc = blockIdx.z;
    int ks = (kc == 0) ? 0 : (33 + 32 * (kc - 1));
    int ke = 33 + 32 * kc;
    if (kc == 0) ke = 33;
    int sr = tid >> 2, sc = (tid & 3) * 8;
    int w = tid >> 6, lane = tid & 63;
    int q = lane >> 4, col = lane & 15;
    int mb = (w >> 1) * 32, nb = (w & 1) * 32;
    floatx4 acc[2][2];
    acc[0][0] = acc[0][1] = acc[1][0] = acc[1][1] = (floatx4){0.f, 0.f, 0.f, 0.f};
    short8 z8 = {0, 0, 0, 0, 0, 0, 0, 0};
    int mA = M0 + sr;
    bool mv = mA < 2000;
    const unsigned short* pa = A + (size_t)mA * KPAD + sc;
    const unsigned short* pb = Bt + (size_t)(N0 + sr) * KPAD + sc;

    for (int kk = ks; kk < ke; kk++) {
        int K0 = kk * 32;
        short8 va = mv ? *(const short8*)(pa + K0) : z8;
        short8 vb = *(const short8*)(pb + K0);
        *(short8*)&As[sr * 40 + sc] = va;
        *(short8*)&Bs[sr * 40 + sc] = vb;
        __syncthreads();
        short8 a0 = *(const short8*)&As[(mb + col) * 40 + q * 8];
        short8 a1 = *(const short8*)&As[(mb + 16 + col) * 40 + q * 8];
        short8 b0 = *(const short8*)&Bs[(nb + col) * 40 + q * 8];
        short8 b1 = *(const short8*)&Bs[(nb + 16 + col) * 40 + q * 8];
        acc[0][0] = __builtin_amdgcn_mfma_f32_16x16x32_bf16(a0, b0, acc[0][0], 0, 0, 0);
        acc[0][1] = __builtin_amdgcn_mfma_f32_16x16x32_bf16(a0, b1, acc[0][1], 0, 0, 0);
        acc[1][0] = __builtin_amdgcn_mfma_f32_16x16x32_bf16(a1, b0, acc[1][0], 0, 0, 0);
        acc[1][1] = __builtin_amdgcn_mfma_f32_16x16x32_bf16(a1, b1, acc[1][1], 0, 0, 0);
        __syncthreads();
    }
    float* out = hpart + (size_t)kc * 1024000;
    #pragma unroll
    for (int mi = 0; mi < 2; mi++)
        #pragma unroll
        for (int ni = 0; ni < 2; ni++)
            #pragma unroll
            for (int rr = 0; rr < 4; rr++) {
                int m = M0 + mb + mi * 16 + q * 4 + rr;
                if (m < 2000)
                    out[m * 512 + N0 + nb + ni * 16 + col] = acc[mi][ni][rr];
            }
}

// reduce 4 partials -> h1t bf16 [bh][f][256], fused GAT1 src/dst scores
__global__ __launch_bounds__(256) void k_hred(const float* __restrict__ hpart,
                                              const float* __restrict__ asrc,
                                              const float* __restrict__ adst,
                                              unsigned short* __restrict__ h1t,
                                              float* __restrict__ ssrc,
                                              float* __restrict__ sdst) {
    int m = blockIdx.x;            // 0..1999
    int tid = threadIdx.x;
    int n1 = tid, n2 = tid + 256;
    size_t base = (size_t)m * 512;
    float s1 = hpart[base + n1] + hpart[base + n1 + 1024000] +
               hpart[base + n1 + 2048000] + hpart[base + n1 + 3072000];
    float s2 = hpart[base + n2] + hpart[base + n2 + 1024000] +
               hpart[base + n2 + 2048000] + hpart[base + n2 + 3072000];
    int bb = m / NNODE, j = m - bb * NNODE;
    int hh1 = n1 >> 6, f1 = n1 & 63;
    int hh2 = n2 >> 6, f2 = n2 & 63;
    h1t[((size_t)((bb * 8 + hh1) * 64 + f1)) * 256 + j] = f2bf(s1);
    h1t[((size_t)((bb * 8 + hh2) * 64 + f2)) * 256 + j] = f2bf(s2);
    float ps1 = s1 * asrc[n1], pd1 = s1 * adst[n1];
    float ps2 = s2 * asrc[n2], pd2 = s2 * adst[n2];
    for (int off = 32; off > 0; off >>= 1) {
        ps1 += __shfl_down(ps1, off); pd1 += __shfl_down(pd1, off);
        ps2 += __shfl_down(ps2, off); pd2 += __shfl_down(pd2, off);
    }
    int lane = tid & 63, w = tid >> 6;
    if (lane == 0) {
        ssrc[m * 8 + w] = ps1;     sdst[m * 8 + w] = pd1;
        ssrc[m * 8 + 4 + w] = ps2; sdst[m * 8 + 4 + w] = pd2;
    }
}

// ---------------- fused GAT1 attention: weights in LDS + MFMA apply ----------------
#define PSTR 264
__global__ __launch_bounds__(256) void k_att1(const float* __restrict__ ssrc,
                                              const float* __restrict__ sdst,
                                              const unsigned short* __restrict__ h1t,
                                              const float* __restrict__ bias,
                                              float* __restrict__ g1) {
    __shared__ __align__(16) unsigned short Ps[128 * PSTR];   // 67584 B
    __shared__ float ss[NNODE];
    __shared__ float red[4];
    int mhalf = blockIdx.x, bh = blockIdx.y;
    int b = bh >> 3, h = bh & 7;
    int tid = threadIdx.x;
    for (int j = tid; j < NNODE; j += 256) ss[j] = ssrc[(b * NNODE + j) * 8 + h];
    __syncthreads();
    float mv = (tid < NNODE) ? ss[tid] : -1e30f;
    for (int off = 32; off > 0; off >>= 1) mv = fmaxf(mv, __shfl_down(mv, off));
    if ((tid & 63) == 0) red[tid >> 6] = mv;
    __syncthreads();
    float smaxv = fmaxf(fmaxf(red[0], red[1]), fmaxf(red[2], red[3]));
    if (tid < 128) {
        unsigned short* row = Ps + tid * PSTR;
        int row_g = mhalf * 128 + tid;
        short8 z8 = {0, 0, 0, 0, 0, 0, 0, 0};
        if (row_g >= NNODE) {
            #pragma unroll
            for (int j = 0; j < 256; j += 8) *(short8*)(row + j) = z8;
        } else {
            float d = sdst[(b * NNODE + row_g) * 8 + h];
            float e0 = d + smaxv;
            float mx = e0 > 0.f ? e0 : 0.2f * e0;
            float den = 0.f;
            for (int j = 0; j < NNODE; j++) {
                float e = d + ss[j];
                e = e > 0.f ? e : 0.2f * e;
                den += __expf(e - mx);
            }
            float rden = 1.f / den;
            for (int j0 = 0; j0 < 256; j0 += 8) {
                unsigned short wv[8];
                #pragma unroll
                for (int jj = 0; jj < 8; jj++) {
                    int j = j0 + jj;
                    float wt = 0.f;
                    if (j < NNODE) {
                        float e = d + ss[j];
                        e = e > 0.f ? e : 0.2f * e;
                        wt = __expf(e - mx) * rden;
                    }
                    wv[jj] = f2bf(wt);
                }
                *(short8*)(row + j0) = *(const short8*)wv;
            }
        }
    }
    __syncthreads();
    int w = tid >> 6, lane = tid & 63;
    int q = lane >> 4, col = lane & 15;
    const unsigned short* Hb = h1t + (size_t)bh * 16384;
    floatx4 acc[2][4];
    #pragma unroll
    for (int mi = 0; mi < 2; mi++)
        #pragma unroll
        for (int ni = 0; ni < 4; ni++)
            acc[mi][ni] = (floatx4){0.f, 0.f, 0.f, 0.f};
    for (int k0 = 0; k0 < 256; k0 += 32) {
        short8 af[2], bf[4];
        #pragma unroll
        for (int mi = 0; mi < 2; mi++)
            af[mi] = *(const short8*)&Ps[((w * 2 + mi) * 16 + col) * PSTR + k0 + q * 8];
        #pragma unroll
        for (int ni = 0; ni < 4; ni++)
            bf[ni] = *(const short8*)(Hb + (size_t)(ni * 16 + col) * 256 + k0 + q * 8);
        #pragma unroll
        for (int mi = 0; mi < 2; mi++)
            #pragma unroll
            for (int ni = 0; ni < 4; ni++)
                acc[mi][ni] = __builtin_amdgcn_mfma_f32_16x16x32_bf16(af[mi], bf[ni], acc[mi][ni], 0, 0, 0);
    }
    #pragma unroll
    for (int mi = 0; mi < 2; mi++)
        #pragma unroll
        for (int ni = 0; ni < 4; ni++)
            #pragma unroll
            for (int rr = 0; rr < 4; rr++) {
                int i = mhalf * 128 + (w * 2 + mi) * 16 + q * 4 + rr;
                int f = ni * 16 + col;
                if (i < NNODE)
                    g1[(b * NNODE + i) * 512 + h * 64 + f] =
                        fmaxf(acc[mi][ni][rr] + bias[h * 64 + f], 0.f);
            }
}

// ---------------- GAT2 ----------------
__global__ __launch_bounds__(256) void k_h2(const float* __restrict__ g1,
                                            const float* __restrict__ W2,
                                            const float* __restrict__ a2src,
                                            const float* __restrict__ a2dst,
                                            unsigned short* __restrict__ h2t,
                                            float* __restrict__ s2src,
                                            float* __restrict__ s2dst) {
    int row = blockIdx.x * 4 + (threadIdx.x >> 6);
    if (row >= 2000) return;
    int lane = threadIdx.x & 63;
    int o = lane & 31, half = lane >> 5;
    const float* gr = &g1[row * 512 + half * 256];
    float acc = 0.f;
    for (int k = 0; k < 256; k++) acc = fmaf(gr[k], W2[(half * 256 + k) * 32 + o], acc);
    acc += __shfl_down(acc, 32);
    float ps = acc * a2src[o], pd = acc * a2dst[o];
    for (int off = 16; off > 0; off >>= 1) {
        ps += __shfl_down(ps, off, 32);
        pd += __shfl_down(pd, off, 32);
    }
    if (lane == 0) { s2src[row] = ps; s2dst[row] = pd; }
    if (lane < 32) {
        int b = row / NNODE, j = row - b * NNODE;
        h2t[((size_t)(b * 32 + o)) * 256 + j] = f2bf(acc);
    }
}

// ---------------- fused GAT2 attention + mean-pool + FC head ----------------
// grid (8): one block per batch.
__global__ __launch_bounds__(256) void k_att2(const float* __restrict__ s2src,
                                              const float* __restrict__ s2dst,
                                              const unsigned short* __restrict__ h2t,
                                              const float* __restrict__ bias2,
                                              const float* __restrict__ fc1w,
                                              const float* __restrict__ fc1b,
                                              const float* __restrict__ bnfg,
                                              const float* __restrict__ bnfb,
                                              const float* __restrict__ fc2w,
                                              const float* __restrict__ fc2b,
                                              float* __restrict__ dout) {
    __shared__ __align__(16) unsigned short Ps[256 * PSTR];   // 135168 B (reused as f32 g-buffer)
    __shared__ float ss[NNODE];
    __shared__ float red[4];
    __shared__ float es2[32];
    __shared__ float zs2[128];
    int b = blockIdx.x;
    int tid = threadIdx.x;
    for (int j = tid; j < NNODE; j += 256) ss[j] = s2src[b * NNODE + j];
    __syncthreads();
    float mv = (tid < NNODE) ? ss[tid] : -1e30f;
    for (int off = 32; off > 0; off >>= 1) mv = fmaxf(mv, __shfl_down(mv, off));
    if ((tid & 63) == 0) red[tid >> 6] = mv;
    __syncthreads();
    float smaxv = fmaxf(fmaxf(red[0], red[1]), fmaxf(red[2], red[3]));
    {
        unsigned short* row = Ps + tid * PSTR;
        short8 z8 = {0, 0, 0, 0, 0, 0, 0, 0};
        if (tid >= NNODE) {
            #pragma unroll
            for (int j = 0; j < 256; j += 8) *(short8*)(row + j) = z8;
        } else {
            float d = s2dst[b * NNODE + tid];
            float e0 = d + smaxv;
            float mx = e0 > 0.f ? e0 : 0.2f * e0;
            float den = 0.f;
            for (int j = 0; j < NNODE; j++) {
                float e = d + ss[j];
                e = e > 0.f ? e : 0.2f * e;
                den += __expf(e - mx);
            }
            float rden = 1.f / den;
            for (int j0 = 0; j0 < 256; j0 += 8) {
                unsigned short wv[8];
                #pragma unroll
                for (int jj = 0; jj < 8; jj++) {
                    int j = j0 + jj;
                    float wt = 0.f;
                    if (j < NNODE) {
                        float e = d + ss[j];
                        e = e > 0.f ? e : 0.2f * e;
                        wt = __expf(e - mx) * rden;
                    }
                    wv[jj] = f2bf(wt);
                }
                *(short8*)(row + j0) = *(const short8*)wv;
            }
        }
    }
    __syncthreads();
    int w = tid >> 6, lane = tid & 63;
    int q = lane >> 4, col = lane & 15;
    const unsigned short* Hb = h2t + (size_t)b * 8192;
    floatx4 acc[4][2];
    #pragma unroll
    for (int mi = 0; mi < 4; mi++)
        #pragma unroll
        for (int ni = 0; ni < 2; ni++)
            acc[mi][ni] = (floatx4){0.f, 0.f, 0.f, 0.f};
    for (int k0 = 0; k0 < 256; k0 += 32) {
        short8 af[4], bf[2];
        #pragma unroll
        for (int mi = 0; mi < 4; mi++)
            af[mi] = *(const short8*)&Ps[((w * 4 + mi) * 16 + col) * PSTR + k0 + q * 8];
        #pragma unroll
        for (int ni = 0; ni < 2; ni++)
            bf[ni] = *(const short8*)(Hb + (size_t)(ni * 16 + col) * 256 + k0 + q * 8);
        #pragma unroll
        for (int mi = 0; mi < 4; mi++)
            #pragma unroll
            for (int ni = 0; ni < 2; ni++)
                acc[mi][ni] = __builtin_amdgcn_mfma_f32_16x16x32_bf16(af[mi], bf[ni], acc[mi][ni], 0, 0, 0);
    }
    __syncthreads();   // all Ps reads complete; reuse as float g-buffer
    float* gf = (float*)Ps;   // [256][33]
    #pragma unroll
    for (int mi = 0; mi < 4; mi++)
        #pragma unroll
        for (int ni = 0; ni < 2; ni++)
            #pragma unroll
            for (int rr = 0; rr < 4; rr++) {
                int i = (w * 4 + mi) * 16 + q * 4 + rr;
                int f = ni * 16 + col;
                gf[i * 33 + f] = acc[mi][ni][rr] + bias2[f];
            }
    __syncthreads();
    // mean-pool (exact k_fc order: i ascending)
    if (tid < 32) {
        int f = tid;
        float s = 0.f;
        for (int i = 0; i < NNODE; i++) s += gf[i * 33 + f];
        s *= (1.0f / 250.0f);
        es2[f] = s;
        dout[16 + b * 32 + f] = s;
    }
    __syncthreads();
    float inv = rsqrtf(1.0f + 1e-5f);
    if (tid < 128) {
        int j = tid;
        float a = fc1b[j];
        #pragma unroll
        for (int k = 0; k < 32; k++) a = fmaf(es2[k], fc1w[k * 128 + j], a);
        a = a * (bnfg[j] * inv) + bnfb[j];
        zs2[j] = fmaxf(a, 0.f);
    }
    __syncthreads();
    if (tid < 2) {
        int o = tid;
        float a = fc2b[o];
        for (int k = 0; k < 128; k++) a = fmaf(zs2[k], fc2w[k * 2 + o], a);
        dout[b * 2 + o] = a;
    }
}

// ---------------- launch ----------------
extern "C" void kernel_launch(void* const* d_in, const int* in_sizes, int n_in,
                              void* d_out, int out_size, void* d_ws, size_t ws_size,
                              hipStream_t stream) {
    (void)in_sizes; (void)n_in; (void)out_size; (void)ws_size;
    const float* x       = (const float*)d_in[0];
    const float* sinc_w  = (const float*)d_in[1];
    const float* conv1_w = (const float*)d_in[2];
    const float* conv1_b = (const float*)d_in[3];
    const float* bn1_g   = (const float*)d_in[4];
    const float* bn1_b   = (const float*)d_in[5];
    const float* conv2_w = (const float*)d_in[6];
    const float* conv2_b = (const float*)d_in[7];
    const float* bn2_g   = (const float*)d_in[8];
    const float* bn2_b   = (const float*)d_in[9];
    const float* gat1_W  = (const float*)d_in[10];
    const float* gat1_as = (const float*)d_in[11];
    const float* gat1_ad = (const float*)d_in[12];
    const float* gat1_bi = (const float*)d_in[13];
    const float* gat2_W  = (const float*)d_in[14];
    const float* gat2_as = (const float*)d_in[15];
    const float* gat2_ad = (const float*)d_in[16];
    const float* gat2_bi = (const float*)d_in[17];
    const float* fc1_w   = (const float*)d_in[18];
    const float* fc1_b   = (const float*)d_in[19];
    const float* bnf_g   = (const float*)d_in[20];
    const float* bnf_b   = (const float*)d_in[21];
    const float* fc2_w   = (const float*)d_in[22];
    const float* fc2_b   = (const float*)d_in[23];
    float* dout = (float*)d_out;

    unsigned short* fh  = (unsigned short*)d_ws;               // 2048*256
    unsigned short* fl  = fh + (size_t)GROWS * 256;
    unsigned short* bch = fl + (size_t)GROWS * 256;            // 576*256 x4
    unsigned short* bcl = bch + (size_t)NBPAD * 256;
    unsigned short* bsh = bcl + (size_t)NBPAD * 256;
    unsigned short* bsl = bsh + (size_t)NBPAD * 256;
    float* GTR = (float*)(bsl + (size_t)NBPAD * 256);          // [576][2048] f32
    float* GTI = GTR + (size_t)GROWS * NBPAD;                  // [576][2048] f32
    float* S0  = GTI + (size_t)GROWS * NBPAD;                  // (dead, layout kept)
    unsigned short* wbt = (unsigned short*)(S0 + 1030104);     // 32*1056
    unsigned short* bpk = wbt + 32 * 1056;                     // 9216
    unsigned short* Bc1 = bpk + 9216;                          // 1024
    unsigned short* Wt  = Bc1 + 1024;                          // 512*KPAD
    unsigned short* nodesb = Wt + (size_t)512 * KPAD;          // 2000*KPAD
    unsigned short* Pn  = nodesb + (size_t)2000 * KPAD;        // (unused, kept for layout)
    unsigned short* h1t = Pn + (size_t)64 * 256 * 256;         // 64*64*256
    unsigned short* h2t = h1t + (size_t)64 * 64 * 256;         // 8*32*256
    unsigned short* P2n = h2t + (size_t)8 * 32 * 256;          // (unused, kept for layout)
    float* hpart = (float*)(P2n + (size_t)8 * 256 * 256);      // 4*1,024,000
    float* ssrc1 = hpart + 4 * 1024000;                        // 16000
    float* sdst1 = ssrc1 + 16000;                              // 16000
    float* g1    = sdst1 + 16000;                              // 1,024,000
    float* s2src = g1 + 1024000;                               // 2000
    float* s2dst = s2src + 2000;                               // 2000

    hipLaunchKernelGGL(k_prep, dim3(3512), dim3(256), 0, stream,
                       x, sinc_w, conv2_w, bn2_g, conv1_w, bn1_g, gat1_W,
                       fh, fl, bch, bcl, bsh, bsl, wbt, bpk, Bc1, Wt, nodesb, h1t, h2t);
    hipLaunchKernelGGL(k_dftsinc, dim3(608), dim3(256), 0, stream,
                       fh, fl, bch, bcl, bsh, bsl, GTR, GTI, x, wbt, nodesb);
    hipLaunchKernelGGL(k_conv2f, dim3(16, 32, 8), dim3(256), 0, stream,
                       GTR, GTI, Bc1, conv1_b, bn1_g, bn1_b, bpk, conv2_b, bn2_g, bn2_b, nodesb);
    hipLaunchKernelGGL(k_gat1s, dim3(8, 32, 4), dim3(256), 0, stream, nodesb, Wt, hpart);
    hipLaunchKernelGGL(k_hred, dim3(2000), dim3(256), 0, stream,
                       hpart, gat1_as, gat1_ad, h1t, ssrc1, sdst1);
    hipLaunchKernelGGL(k_att1, dim3(2, 64), dim3(256), 0, stream,
                       ssrc1, sdst1, h1t, gat1_bi, g1);
    hipLaunchKernelGGL(k_h2, dim3(500), dim3(256), 0, stream,
                       g1, gat2_W, gat2_as, gat2_ad, h2t, s2src, s2dst);
    hipLaunchKernelGGL(k_att2, dim3(8), dim3(256), 0, stream,
                       s2src, s2dst, h2t, gat2_bi,
                       fc1_w, fc1_b, bnf_g, bnf_b, fc2_w, fc2_b, dout);
}

// Round 13
// 291.409 us; speedup vs baseline: 1.0333x; 1.0333x over previous
//
#include <hip/hip_runtime.h>
#include <hip/hip_bf16.h>
#include <math.h>

// ---------------- constants ----------------
#define TB 8
#define TT 64000
#define NFRAMES 251
#define NROWS (TB*NFRAMES)      // 2008
#define GROWS 2048              // 8 * 256 radix-4 sub-rows
#define NBINS 513
#define NBPAD 576
#define NNODE 250
#define NODE_DIM 4116
#define KPAD 4128

typedef __attribute__((ext_vector_type(8))) short short8;
typedef __attribute__((ext_vector_type(4))) float floatx4;

static __device__ __forceinline__ unsigned short f2bf(float x) {
    __hip_bfloat16 h = __float2bfloat16(x);
    return *(unsigned short*)&h;
}
static __device__ __forceinline__ float bf2f(unsigned short u) {
    __hip_bfloat16 h = *(__hip_bfloat16*)&u;
    return __bfloat162float(h);
}

// ---------------- merged prep kernel: all input-only transforms in ONE launch ----------------
__global__ __launch_bounds__(256) void k_prep(
    const float* __restrict__ x, const float* __restrict__ sinc_w,
    const float* __restrict__ c2w, const float* __restrict__ g2bn,
    const float* __restrict__ c1w, const float* __restrict__ g1bn,
    const float* __restrict__ W,
    unsigned short* __restrict__ fh, unsigned short* __restrict__ fl,
    unsigned short* __restrict__ bch, unsigned short* __restrict__ bcl,
    unsigned short* __restrict__ bsh, unsigned short* __restrict__ bsl,
    unsigned short* __restrict__ wbt, unsigned short* __restrict__ Bp,
    unsigned short* __restrict__ Bc1,
    unsigned short* __restrict__ Wt, unsigned short* __restrict__ nodesb,
    unsigned short* __restrict__ h1t, unsigned short* __restrict__ h2t) {
    __shared__ unsigned short tile[64][65];
    int bi = blockIdx.x, tid = threadIdx.x;
    if (bi < 2048) {
        int idx = bi * 256 + tid;
        int row = idx >> 8, r = idx & 255;
        int b = row >> 8, j = row & 255;
        int u = j * 256 + r - 512;
        if (u < 0) u = -u;
        if (u >= TT) u = 2 * TT - 2 - u;
        float v = x[b * TT + u];
        unsigned short h = f2bf(v);
        fh[idx] = h;
        fl[idx] = f2bf(v - bf2f(h));
    } else if (bi < 2624) {
        int idx = (bi - 2048) * 256 + tid;
        int k = idx >> 8, r = idx & 255;
        float s = 0.f, c = 0.f;
        if (k < NBINS) {
            int mm = (k * r) & 1023;
            sincospif((float)mm * (1.0f / 512.0f), &s, &c);
        }
        unsigned short chv = f2bf(c), shv = f2bf(s);
        bch[idx] = chv; bcl[idx] = f2bf(c - bf2f(chv));
        bsh[idx] = shv; bsl[idx] = f2bf(s - bf2f(shv));
    } else if (bi < 3144) {
        int local = bi - 2624;
        int kt = local % 65, nt = local / 65;
        for (int idx = tid; idx < 4096; idx += 256) {
            int r = idx >> 6, c = idx & 63;
            int kp = kt * 64 + r;
            int k;
            if (kp < 20) k = kp;
            else if (kp < NODE_DIM) { int t = kp - 20; k = 20 + (t & 15) * 256 + (t >> 4); }
            else k = -1;
            float v = (k >= 0) ? W[k * 512 + nt * 64 + c] : 0.f;
            tile[r][c] = f2bf(v);
        }
        __syncthreads();
        for (int idx = tid; idx < 4096; idx += 256) {
            int nl = idx >> 6, kl = idx & 63;
            int k = kt * 64 + kl;
            if (k < KPAD)
                Wt[(size_t)(nt * 64 + nl) * KPAD + k] = tile[kl][nl];
        }
    } else if (bi < 3276) {
        int idx = (bi - 3144) * 256 + tid;
        if (idx < 32 * 1056) {
            int c = idx / 1056, m = idx - c * 1056;
            float s = 0.f;
            if (c < 20 && m < 1027) {
                #pragma unroll
                for (int d = 0; d < 4; d++) {
                    int k = m - d;
                    if (k >= 0 && k < 1024) s += sinc_w[c * 1024 + k];
                }
                s *= 0.25f;
            }
            wbt[idx] = f2bf(s);
        }
    } else if (bi < 3312) {
        int idx = (bi - 3276) * 256 + tid;
        if (idx < 9216) {
            int j = idx & 7, lane = (idx >> 3) & 63, ct = (idx >> 9) & 1, s = idx >> 10;
            int co = ct * 16 + (lane & 15);
            int ci = (lane >> 4) * 8 + j;
            float inv = rsqrtf(1.0f + 1e-5f);
            Bp[idx] = f2bf(c2w[co * 288 + ci * 9 + s] * (g2bn[co] * inv));
        }
    } else if (bi < 3508) {
        int idx = (bi - 3312) * 256 + tid;
        if (idx < 24000) {
            int row = idx / 12, c = idx - row * 12;
            nodesb[(size_t)row * KPAD + 4116 + c] = 0;
        } else if (idx < 48576) {
            int t = idx - 24000; int r = t / 6, c = t - r * 6;
            h1t[(size_t)r * 256 + 250 + c] = 0;
        } else if (idx < 50112) {
            int t = idx - 48576; int r = t / 6, c = t - r * 6;
            h2t[(size_t)r * 256 + 250 + c] = 0;
        }
    } else {
        // conv1 weight B-fragments: Bc1[ch=32][k=32], hi/lo 3-term layout
        int idx = (bi - 3508) * 256 + tid;
        if (idx < 1024) {
            int ch = idx >> 5, k = idx & 31;
            float inv = rsqrtf(1.0f + 1e-5f);
            int t; int typ; // 0=hi 1=lo 2=zero
            if (k < 8)       { t = k;      typ = 0; }
            else if (k < 16) { t = k - 8;  typ = 0; }
            else if (k < 24) { t = k - 16; typ = 1; }
            else if (k == 24 || k == 25) { t = 8; typ = 0; }
            else if (k == 26) { t = 8; typ = 1; }
            else { t = 0; typ = 2; }
            unsigned short outv = 0;
            if (typ != 2) {
                float wv = c1w[ch * 9 + t] * (g1bn[ch] * inv);
                unsigned short whi = f2bf(wv);
                outv = (typ == 0) ? whi : f2bf(wv - bf2f(whi));
            }
            Bc1[idx] = outv;
        }
    }
}

// ---------------- radix-4 DFT GEMM (transposed GT[bin][row] output) + sinc conv, one launch ----------------
__global__ __launch_bounds__(256) void k_dftsinc(const unsigned short* __restrict__ fh,
                                                 const unsigned short* __restrict__ fl,
                                                 const unsigned short* __restrict__ ch,
                                                 const unsigned short* __restrict__ cl,
                                                 const unsigned short* __restrict__ sh,
                                                 const unsigned short* __restrict__ sl,
                                                 float* __restrict__ GTR,
                                                 float* __restrict__ GTI,
                                                 const float* __restrict__ x,
                                                 const unsigned short* __restrict__ wbt,
                                                 unsigned short* __restrict__ nodesb) {
    __shared__ __align__(16) unsigned char smem[34048];
    int tid = threadIdx.x;
    int bi = blockIdx.x;
    if (bi >= 576) {
        // ---- sinc conv as MFMA GEMM, M-split ----
        unsigned short* xs = (unsigned short*)smem;   // 1312 ush
        int local = bi - 576;
        int ut = local & 3, b = local >> 2;
        int base = 256 * ut - 512;
        for (int i = tid; i < 1312; i += 256) {
            int g = base + i;
            float v = (g >= 0 && g < TT) ? x[b * TT + g] : 0.f;
            xs[i] = f2bf(v);
        }
        __syncthreads();
        int w = tid >> 6, lane = tid & 63;
        int q = lane >> 4, col = lane & 15;
        floatx4 acc[2];
        acc[0] = acc[1] = (floatx4){0.f, 0.f, 0.f, 0.f};
        for (int K0 = 0; K0 < 1056; K0 += 32) {
            int off = 4 * (w * 16 + col) + K0 + q * 8;
            unsigned long long lo = *(const unsigned long long*)&xs[off];
            unsigned long long hi = *(const unsigned long long*)&xs[off + 4];
            union { unsigned long long u64[2]; short8 s8; } cv;
            cv.u64[0] = lo; cv.u64[1] = hi;
            short8 af = cv.s8;
            #pragma unroll
            for (int ni = 0; ni < 2; ni++) {
                short8 bf = *(const short8*)(wbt + (size_t)(ni * 16 + col) * 1056 + K0 + q * 8);
                acc[ni] = __builtin_amdgcn_mfma_f32_16x16x32_bf16(af, bf, acc[ni], 0, 0, 0);
            }
        }
        #pragma unroll
        for (int ni = 0; ni < 2; ni++)
            #pragma unroll
            for (int rr = 0; rr < 4; rr++) {
                int u = ut * 64 + w * 16 + q * 4 + rr;
                int c = ni * 16 + col;
                if (u < NNODE && c < 20)
                    nodesb[(size_t)(b * NNODE + u) * KPAD + c] = f2bf(acc[ni][rr]);
            }
        return;
    }
    // ---- DFT part ----
    unsigned short* Ah  = (unsigned short*)smem;             // 2560 B
    unsigned short* Al  = (unsigned short*)(smem + 2560);    // 2560 B
    unsigned short* Bch = (unsigned short*)(smem + 5120);    // 5120 B
    unsigned short* Bcl = (unsigned short*)(smem + 10240);
    unsigned short* Bsh = (unsigned short*)(smem + 15360);
    unsigned short* Bsl = (unsigned short*)(smem + 20480);
    float* TR = (float*)(smem + 25600);                      // 64*33*4 = 8448 B
    int N0 = (bi % 9) * 64, M0 = (bi / 9) * 32;
    int br = tid >> 2, bc = (tid & 3) * 8;
    size_t boff = (size_t)(N0 + br) * 256 + bc;
    int ar = (tid & 127) >> 2, ac = (tid & 3) * 8;
    size_t aoff = (size_t)(M0 + ar) * 256 + ac;
    bool loA = tid < 128;
    int w = tid >> 6, lane = tid & 63;
    int q = lane >> 4, col = lane & 15;
    int mb = (w >> 1) * 16, nb = (w & 1) * 32;
    floatx4 aR[2], aI[2];
    aR[0] = aR[1] = aI[0] = aI[1] = (floatx4){0.f, 0.f, 0.f, 0.f};

    for (int K0 = 0; K0 < 256; K0 += 32) {
        if (loA) *(short8*)&Ah[ar * 40 + ac] = *(const short8*)(fh + aoff + K0);
        else     *(short8*)&Al[ar * 40 + ac] = *(const short8*)(fl + aoff + K0);
        *(short8*)&Bch[br * 40 + bc] = *(const short8*)(ch + boff + K0);
        *(short8*)&Bcl[br * 40 + bc] = *(const short8*)(cl + boff + K0);
        *(short8*)&Bsh[br * 40 + bc] = *(const short8*)(sh + boff + K0);
        *(short8*)&Bsl[br * 40 + bc] = *(const short8*)(sl + boff + K0);
        __syncthreads();
        short8 ahv = *(const short8*)&Ah[(mb + col) * 40 + q * 8];
        short8 alv = *(const short8*)&Al[(mb + col) * 40 + q * 8];
        #pragma unroll
        for (int ni = 0; ni < 2; ni++) {
            short8 chv = *(const short8*)&Bch[(nb + ni * 16 + col) * 40 + q * 8];
            short8 clv = *(const short8*)&Bcl[(nb + ni * 16 + col) * 40 + q * 8];
            short8 shv = *(const short8*)&Bsh[(nb + ni * 16 + col) * 40 + q * 8];
            short8 slv = *(const short8*)&Bsl[(nb + ni * 16 + col) * 40 + q * 8];
            aR[ni] = __builtin_amdgcn_mfma_f32_16x16x32_bf16(ahv, chv, aR[ni], 0, 0, 0);
            aR[ni] = __builtin_amdgcn_mfma_f32_16x16x32_bf16(ahv, clv, aR[ni], 0, 0, 0);
            aR[ni] = __builtin_amdgcn_mfma_f32_16x16x32_bf16(alv, chv, aR[ni], 0, 0, 0);
            aI[ni] = __builtin_amdgcn_mfma_f32_16x16x32_bf16(ahv, shv, aI[ni], 0, 0, 0);
            aI[ni] = __builtin_amdgcn_mfma_f32_16x16x32_bf16(ahv, slv, aI[ni], 0, 0, 0);
            aI[ni] = __builtin_amdgcn_mfma_f32_16x16x32_bf16(alv, shv, aI[ni], 0, 0, 0);
        }
        __syncthreads();
    }
    // transpose epilogue via LDS: coalesced GT[bin][row] writes
    int bin_l = tid >> 2, ms = (tid & 3) * 8;
    #pragma unroll
    for (int ni = 0; ni < 2; ni++)
        #pragma unroll
        for (int rr = 0; rr < 4; rr++)
            TR[(nb + ni * 16 + col) * 33 + mb + q * 4 + rr] = aR[ni][rr];
    __syncthreads();
    {
        float* dst = GTR + (size_t)(N0 + bin_l) * 2048 + M0 + ms;
        #pragma unroll
        for (int j = 0; j < 8; j++) dst[j] = TR[bin_l * 33 + ms + j];
    }
    __syncthreads();
    #pragma unroll
    for (int ni = 0; ni < 2; ni++)
        #pragma unroll
        for (int rr = 0; rr < 4; rr++)
            TR[(nb + ni * 16 + col) * 33 + mb + q * 4 + rr] = aI[ni][rr];
    __syncthreads();
    {
        float* dst = GTI + (size_t)(N0 + bin_l) * 2048 + M0 + ms;
        #pragma unroll
        for (int j = 0; j < 8; j++) dst[j] = TR[bin_l * 33 + ms + j];
    }
}

// ---------------- fused conv1+conv2; S0 tile computed inline from GT ----------------
#define O1STR 40
__global__ __launch_bounds__(256) void k_conv2f(const float* __restrict__ GTR,
                                                const float* __restrict__ GTI,
                                                const unsigned short* __restrict__ Bc1,
                                                const float* __restrict__ c1b,
                                                const float* __restrict__ g1bn,
                                                const float* __restrict__ b1bn,
                                                const unsigned short* __restrict__ Bp,
                                                const float* __restrict__ c2b,
                                                const float* __restrict__ g2bn,
                                                const float* __restrict__ b2bn,
                                                unsigned short* __restrict__ nodesb) {
    __shared__ __align__(16) unsigned short o1s[18 * 18 * O1STR];  // 25920 B
    __shared__ float S0s[20][20];
    __shared__ float b1s[32];
    __shared__ float b2s[32];
    int tid = threadIdx.x;
    int b = blockIdx.z;
    int F0 = blockIdx.y * 8;
    int T0 = blockIdx.x * 8;
    float inv = rsqrtf(1.0f + 1e-5f);
    if (tid < 32) {
        b1s[tid] = c1b[tid] * (g1bn[tid] * inv) + b1bn[tid];
        b2s[tid] = c2b[tid] * (g2bn[tid] * inv) + b2bn[tid];
    }
    for (int i = tid; i < 400; i += 256) {
        int r = i / 20, c = i - r * 20;
        int bin = 2 * F0 - 2 + r, fr = 2 * T0 - 2 + c;
        float v = 0.f;
        if (bin >= 0 && bin < 513 && fr >= 0 && fr < 251) {
            size_t base = (size_t)bin * 2048 + b * 256 + fr;
            float gr0 = GTR[base], gr1 = GTR[base + 1], gr2 = GTR[base + 2], gr3 = GTR[base + 3];
            float gs0 = GTI[base], gs1 = GTI[base + 1], gs2 = GTI[base + 2], gs3 = GTI[base + 3];
            float fre, fim;
            switch (bin & 3) {
                case 0: fre = gr0 + gr1 + gr2 + gr3; fim = gs0 + gs1 + gs2 + gs3; break;
                case 1: fre = gr0 - gs1 - gr2 + gs3; fim = gs0 + gr1 - gs2 - gr3; break;
                case 2: fre = gr0 - gr1 + gr2 - gr3; fim = gs0 - gs1 + gs2 - gs3; break;
                default: fre = gr0 + gs1 - gr2 - gs3; fim = gs0 - gr1 - gs2 + gr3; break;
            }
            v = logf(sqrtf(fmaf(fre, fre, fim * fim)) + 1e-9f);
        }
        S0s[r][c] = v;
    }
    __syncthreads();

    int lane = tid & 63, w = tid >> 6;
    int q = lane >> 4, col = lane & 15;

    // ---- conv1 as MFMA: positions p = r*18+t (324), channels 32, K=32 packed hi/lo ----
    {
        short8 bfr0 = *(const short8*)(Bc1 + (size_t)col * 32 + q * 8);
        short8 bfr1 = *(const short8*)(Bc1 + (size_t)(16 + col) * 32 + q * 8);
        for (int mt = w; mt < 21; mt += 4) {
            int p = mt * 16 + col;
            int pc = p < 324 ? p : 0;
            int pr = (pc * 228) >> 12;      // pc/18
            int pt = pc - pr * 18;
            float tv[9];
            #pragma unroll
            for (int di = 0; di < 3; di++)
                #pragma unroll
                for (int dj = 0; dj < 3; dj++)
                    tv[di * 3 + dj] = S0s[pr + di][pt + dj];
            unsigned short hu[9], lu[9];
            #pragma unroll
            for (int i = 0; i < 9; i++) {
                hu[i] = f2bf(tv[i]);
                lu[i] = f2bf(tv[i] - bf2f(hu[i]));
            }
            short8 af;
            if (q == 1) {
                af[0] = lu[0]; af[1] = lu[1]; af[2] = lu[2]; af[3] = lu[3];
                af[4] = lu[4]; af[5] = lu[5]; af[6] = lu[6]; af[7] = lu[7];
            } else if (q == 3) {
                af[0] = hu[8]; af[1] = lu[8]; af[2] = hu[8]; af[3] = 0;
                af[4] = 0; af[5] = 0; af[6] = 0; af[7] = 0;
            } else {
                af[0] = hu[0]; af[1] = hu[1]; af[2] = hu[2]; af[3] = hu[3];
                af[4] = hu[4]; af[5] = hu[5]; af[6] = hu[6]; af[7] = hu[7];
            }
            floatx4 c0 = (floatx4){0.f, 0.f, 0.f, 0.f};
            floatx4 c1 = (floatx4){0.f, 0.f, 0.f, 0.f};
            c0 = __builtin_amdgcn_mfma_f32_16x16x32_bf16(af, bfr0, c0, 0, 0, 0);
            c1 = __builtin_amdgcn_mfma_f32_16x16x32_bf16(af, bfr1, c1, 0, 0, 0);
            #pragma unroll
            for (int rr2 = 0; rr2 < 4; rr2++) {
                int pp = mt * 16 + q * 4 + rr2;
                if (pp < 324) {
                    int qr = (pp * 228) >> 12, qt = pp - qr * 18;
                    int r1 = 2 * F0 - 1 + qr, t1 = 2 * T0 - 1 + qt;
                    bool valid = (r1 >= 0 && r1 < 513 && t1 >= 0 && t1 < 251);
                    float v0 = fmaxf(c0[rr2] + b1s[col], 0.f);
                    float v1 = fmaxf(c1[rr2] + b1s[16 + col], 0.f);
                    o1s[pp * O1STR + col]      = valid ? f2bf(v0) : (unsigned short)0;
                    o1s[pp * O1STR + 16 + col] = valid ? f2bf(v1) : (unsigned short)0;
                }
            }
        }
    }
    __syncthreads();

    floatx4 acc[4][2];
    #pragma unroll
    for (int rt = 0; rt < 4; rt++)
        #pragma unroll
        for (int ct = 0; ct < 2; ct++)
            acc[rt][ct] = (floatx4){0.f, 0.f, 0.f, 0.f};

    #pragma unroll
    for (int s = 0; s < 9; s++) {
        const int di = s / 3, dj = s % 3;
        short8 bf0 = *(const short8*)&Bp[(s * 2 + 0) * 512 + lane * 8];
        short8 bf1 = *(const short8*)&Bp[(s * 2 + 1) * 512 + lane * 8];
        #pragma unroll
        for (int rt = 0; rt < 4; rt++) {
            short8 af = *(const short8*)&o1s[((w * 4 + rt + di) * 18 + (col + dj)) * O1STR + q * 8];
            acc[rt][0] = __builtin_amdgcn_mfma_f32_16x16x32_bf16(af, bf0, acc[rt][0], 0, 0, 0);
            acc[rt][1] = __builtin_amdgcn_mfma_f32_16x16x32_bf16(af, bf1, acc[rt][1], 0, 0, 0);
        }
    }
    __syncthreads();

    unsigned short* nb = o1s;
    #pragma unroll
    for (int ct = 0; ct < 2; ct++) {
        float bb = b2s[ct * 16 + col];
        #pragma unroll
        for (int fp2 = 0; fp2 < 2; fp2++)
            #pragma unroll
            for (int tc2 = 0; tc2 < 2; tc2++) {
                float m0 = fmaxf(
                    fmaxf(acc[2 * fp2][ct][2 * tc2], acc[2 * fp2][ct][2 * tc2 + 1]),
                    fmaxf(acc[2 * fp2 + 1][ct][2 * tc2], acc[2 * fp2 + 1][ct][2 * tc2 + 1]));
                float v = fmaxf(m0 + bb, 0.f);
                int nl = (2 * q + tc2) * 2 + ct;   // 0..15
                int fl = 2 * w + fp2;              // 0..7
                nb[nl * 136 + fl * 16 + col] = f2bf(v);
            }
    }
    __syncthreads();

    int nl = tid >> 4, part = tid & 15;
    int node_g = 2 * T0 + nl;
    if (node_g < NNODE) {
        unsigned short* dst = nodesb + (size_t)(b * NNODE + node_g) * KPAD + 20 + F0 * 16 + part * 8;
        *(short8*)(dst) = *(const short8*)&nb[nl * 136 + part * 8];
    }
}

// ---------------- GAT1 GEMM split-K (bf16 MFMA): hpart[kc][2000][512] ----------------
__global__ __launch_bounds__(256) void k_gat1s(const unsigned short* __restrict__ A,
                                               const unsigned short* __restrict__ Bt,
                                               float* __restrict__ hpart) {
    __shared__ __align__(16) unsigned short As[64 * 40];
    __shared__ __align__(16) unsigned short Bs[64 * 40];
    int tid = threadIdx.x;
    int N0 = blockIdx.x * 64, M0 = blockIdx.y * 64;
    int kc = blockIdx.z;
    int ks = (kc == 0) ? 0 : (33 + 32 * (kc - 1));
    int ke = 33 + 32 * kc;
    if (kc == 0) ke = 33;
    int sr = tid >> 2, sc = (tid & 3) * 8;
    int w = tid >> 6, lane = tid & 63;
    int q = lane >> 4, col = lane & 15;
    int mb = (w >> 1) * 32, nb = (w & 1) * 32;
    floatx4 acc[2][2];
    acc[0][0] = acc[0][1] = acc[1][0] = acc[1][1] = (floatx4){0.f, 0.f, 0.f, 0.f};
    short8 z8 = {0, 0, 0, 0, 0, 0, 0, 0};
    int mA = M0 + sr;
    bool mv = mA < 2000;
    const unsigned short* pa = A + (size_t)mA * KPAD + sc;
    const unsigned short* pb = Bt + (size_t)(N0 + sr) * KPAD + sc;

    for (int kk = ks; kk < ke; kk++) {
        int K0 = kk * 32;
        short8 va = mv ? *(const short8*)(pa + K0) : z8;
        short8 vb = *(const short8*)(pb + K0);
        *(short8*)&As[sr * 40 + sc] = va;
        *(short8*)&Bs[sr * 40 + sc] = vb;
        __syncthreads();
        short8 a0 = *(const short8*)&As[(mb + col) * 40 + q * 8];
        short8 a1 = *(const short8*)&As[(mb + 16 + col) * 40 + q * 8];
        short8 b0 = *(const short8*)&Bs[(nb + col) * 40 + q * 8];
        short8 b1 = *(const short8*)&Bs[(nb + 16 + col) * 40 + q * 8];
        acc[0][0] = __builtin_amdgcn_mfma_f32_16x16x32_bf16(a0, b0, acc[0][0], 0, 0, 0);
        acc[0][1] = __builtin_amdgcn_mfma_f32_16x16x32_bf16(a0, b1, acc[0][1], 0, 0, 0);
        acc[1][0] = __builtin_amdgcn_mfma_f32_16x16x32_bf16(a1, b0, acc[1][0], 0, 0, 0);
        acc[1][1] = __builtin_amdgcn_mfma_f32_16x16x32_bf16(a1, b1, acc[1][1], 0, 0, 0);
        __syncthreads();
    }
    float* out = hpart + (size_t)kc * 1024000;
    #pragma unroll
    for (int mi = 0; mi < 2; mi++)
        #pragma unroll
        for (int ni = 0; ni < 2; ni++)
            #pragma unroll
            for (int rr = 0; rr < 4; rr++) {
                int m = M0 + mb + mi * 16 + q * 4 + rr;
                if (m < 2000)
                    out[m * 512 + N0 + nb + ni * 16 + col] = acc[mi][ni][rr];
            }
}

// reduce 4 partials -> h1t bf16 [bh][f][256], fused GAT1 src/dst scores
__global__ __launch_bounds__(256) void k_hred(const float* __restrict__ hpart,
                                              const float* __restrict__ asrc,
                                              const float* __restrict__ adst,
                                              unsigned short* __restrict__ h1t,
                                              float* __restrict__ ssrc,
                                              float* __restrict__ sdst) {
    int m = blockIdx.x;            // 0..1999
    int tid = threadIdx.x;
    int n1 = tid, n2 = tid + 256;
    size_t base = (size_t)m * 512;
    float s1 = hpart[base + n1] + hpart[base + n1 + 1024000] +
               hpart[base + n1 + 2048000] + hpart[base + n1 + 3072000];
    float s2 = hpart[base + n2] + hpart[base + n2 + 1024000] +
               hpart[base + n2 + 2048000] + hpart[base + n2 + 3072000];
    int bb = m / NNODE, j = m - bb * NNODE;
    int hh1 = n1 >> 6, f1 = n1 & 63;
    int hh2 = n2 >> 6, f2 = n2 & 63;
    h1t[((size_t)((bb * 8 + hh1) * 64 + f1)) * 256 + j] = f2bf(s1);
    h1t[((size_t)((bb * 8 + hh2) * 64 + f2)) * 256 + j] = f2bf(s2);
    float ps1 = s1 * asrc[n1], pd1 = s1 * adst[n1];
    float ps2 = s2 * asrc[n2], pd2 = s2 * adst[n2];
    for (int off = 32; off > 0; off >>= 1) {
        ps1 += __shfl_down(ps1, off); pd1 += __shfl_down(pd1, off);
        ps2 += __shfl_down(ps2, off); pd2 += __shfl_down(pd2, off);
    }
    int lane = tid & 63, w = tid >> 6;
    if (lane == 0) {
        ssrc[m * 8 + w] = ps1;     sdst[m * 8 + w] = pd1;
        ssrc[m * 8 + 4 + w] = ps2; sdst[m * 8 + 4 + w] = pd2;
    }
}

// ---------------- fused GAT1 attention: weights in LDS + MFMA apply ----------------
#define PSTR 264
__global__ __launch_bounds__(256) void k_att1(const float* __restrict__ ssrc,
                                              const float* __restrict__ sdst,
                                              const unsigned short* __restrict__ h1t,
                                              const float* __restrict__ bias,
                                              float* __restrict__ g1) {
    __shared__ __align__(16) unsigned short Ps[128 * PSTR];   // 67584 B
    __shared__ float ss[NNODE];
    __shared__ float red[4];
    int mhalf = blockIdx.x, bh = blockIdx.y;
    int b = bh >> 3, h = bh & 7;
    int tid = threadIdx.x;
    for (int j = tid; j < NNODE; j += 256) ss[j] = ssrc[(b * NNODE + j) * 8 + h];
    __syncthreads();
    float mv = (tid < NNODE) ? ss[tid] : -1e30f;
    for (int off = 32; off > 0; off >>= 1) mv = fmaxf(mv, __shfl_down(mv, off));
    if ((tid & 63) == 0) red[tid >> 6] = mv;
    __syncthreads();
    float smaxv = fmaxf(fmaxf(red[0], red[1]), fmaxf(red[2], red[3]));
    if (tid < 128) {
        unsigned short* row = Ps + tid * PSTR;
        int row_g = mhalf * 128 + tid;
        short8 z8 = {0, 0, 0, 0, 0, 0, 0, 0};
        if (row_g >= NNODE) {
            #pragma unroll
            for (int j = 0; j < 256; j += 8) *(short8*)(row + j) = z8;
        } else {
            float d = sdst[(b * NNODE + row_g) * 8 + h];
            float e0 = d + smaxv;
            float mx = e0 > 0.f ? e0 : 0.2f * e0;
            float den = 0.f;
            for (int j = 0; j < NNODE; j++) {
                float e = d + ss[j];
                e = e > 0.f ? e : 0.2f * e;
                den += __expf(e - mx);
            }
            float rden = 1.f / den;
            for (int j0 = 0; j0 < 256; j0 += 8) {
                unsigned short wv[8];
                #pragma unroll
                for (int jj = 0; jj < 8; jj++) {
                    int j = j0 + jj;
                    float wt = 0.f;
                    if (j < NNODE) {
                        float e = d + ss[j];
                        e = e > 0.f ? e : 0.2f * e;
                        wt = __expf(e - mx) * rden;
                    }
                    wv[jj] = f2bf(wt);
                }
                *(short8*)(row + j0) = *(const short8*)wv;
            }
        }
    }
    __syncthreads();
    int w = tid >> 6, lane = tid & 63;
    int q = lane >> 4, col = lane & 15;
    const unsigned short* Hb = h1t + (size_t)bh * 16384;
    floatx4 acc[2][4];
    #pragma unroll
    for (int mi = 0; mi < 2; mi++)
        #pragma unroll
        for (int ni = 0; ni < 4; ni++)
            acc[mi][ni] = (floatx4){0.f, 0.f, 0.f, 0.f};
    for (int k0 = 0; k0 < 256; k0 += 32) {
        short8 af[2], bf[4];
        #pragma unroll
        for (int mi = 0; mi < 2; mi++)
            af[mi] = *(const short8*)&Ps[((w * 2 + mi) * 16 + col) * PSTR + k0 + q * 8];
        #pragma unroll
        for (int ni = 0; ni < 4; ni++)
            bf[ni] = *(const short8*)(Hb + (size_t)(ni * 16 + col) * 256 + k0 + q * 8);
        #pragma unroll
        for (int mi = 0; mi < 2; mi++)
            #pragma unroll
            for (int ni = 0; ni < 4; ni++)
                acc[mi][ni] = __builtin_amdgcn_mfma_f32_16x16x32_bf16(af[mi], bf[ni], acc[mi][ni], 0, 0, 0);
    }
    #pragma unroll
    for (int mi = 0; mi < 2; mi++)
        #pragma unroll
        for (int ni = 0; ni < 4; ni++)
            #pragma unroll
            for (int rr = 0; rr < 4; rr++) {
                int i = mhalf * 128 + (w * 2 + mi) * 16 + q * 4 + rr;
                int f = ni * 16 + col;
                if (i < NNODE)
                    g1[(b * NNODE + i) * 512 + h * 64 + f] =
                        fmaxf(acc[mi][ni][rr] + bias[h * 64 + f], 0.f);
            }
}

// ---------------- GAT2 ----------------
__global__ __launch_bounds__(256) void k_h2(const float* __restrict__ g1,
                                            const float* __restrict__ W2,
                                            const float* __restrict__ a2src,
                                            const float* __restrict__ a2dst,
                                            unsigned short* __restrict__ h2t,
                                            float* __restrict__ s2src,
                                            float* __restrict__ s2dst) {
    int row = blockIdx.x * 4 + (threadIdx.x >> 6);
    if (row >= 2000) return;
    int lane = threadIdx.x & 63;
    int o = lane & 31, half = lane >> 5;
    const float* gr = &g1[row * 512 + half * 256];
    float acc = 0.f;
    for (int k = 0; k < 256; k++) acc = fmaf(gr[k], W2[(half * 256 + k) * 32 + o], acc);
    acc += __shfl_down(acc, 32);
    float ps = acc * a2src[o], pd = acc * a2dst[o];
    for (int off = 16; off > 0; off >>= 1) {
        ps += __shfl_down(ps, off, 32);
        pd += __shfl_down(pd, off, 32);
    }
    if (lane == 0) { s2src[row] = ps; s2dst[row] = pd; }
    if (lane < 32) {
        int b = row / NNODE, j = row - b * NNODE;
        h2t[((size_t)(b * 32 + o)) * 256 + j] = f2bf(acc);
    }
}

// ---------------- fused GAT2 attention + mean-pool + FC head ----------------
// grid (8): one block per batch.
__global__ __launch_bounds__(256) void k_att2(const float* __restrict__ s2src,
                                              const float* __restrict__ s2dst,
                                              const unsigned short* __restrict__ h2t,
                                              const float* __restrict__ bias2,
                                              const float* __restrict__ fc1w,
                                              const float* __restrict__ fc1b,
                                              const float* __restrict__ bnfg,
                                              const float* __restrict__ bnfb,
                                              const float* __restrict__ fc2w,
                                              const float* __restrict__ fc2b,
                                              float* __restrict__ dout) {
    __shared__ __align__(16) unsigned short Ps[256 * PSTR];   // 135168 B (reused as f32 g-buffer)
    __shared__ float ss[NNODE];
    __shared__ float red[4];
    __shared__ float es2[32];
    __shared__ float zs2[128];
    int b = blockIdx.x;
    int tid = threadIdx.x;
    for (int j = tid; j < NNODE; j += 256) ss[j] = s2src[b * NNODE + j];
    __syncthreads();
    float mv = (tid < NNODE) ? ss[tid] : -1e30f;
    for (int off = 32; off > 0; off >>= 1) mv = fmaxf(mv, __shfl_down(mv, off));
    if ((tid & 63) == 0) red[tid >> 6] = mv;
    __syncthreads();
    float smaxv = fmaxf(fmaxf(red[0], red[1]), fmaxf(red[2], red[3]));
    {
        unsigned short* row = Ps + tid * PSTR;
        short8 z8 = {0, 0, 0, 0, 0, 0, 0, 0};
        if (tid >= NNODE) {
            #pragma unroll
            for (int j = 0; j < 256; j += 8) *(short8*)(row + j) = z8;
        } else {
            float d = s2dst[b * NNODE + tid];
            float e0 = d + smaxv;
            float mx = e0 > 0.f ? e0 : 0.2f * e0;
            float den = 0.f;
            for (int j = 0; j < NNODE; j++) {
                float e = d + ss[j];
                e = e > 0.f ? e : 0.2f * e;
                den += __expf(e - mx);
            }
            float rden = 1.f / den;
            for (int j0 = 0; j0 < 256; j0 += 8) {
                unsigned short wv[8];
                #pragma unroll
                for (int jj = 0; jj < 8; jj++) {
                    int j = j0 + jj;
                    float wt = 0.f;
                    if (j < NNODE) {
                        float e = d + ss[j];
                        e = e > 0.f ? e : 0.2f * e;
                        wt = __expf(e - mx) * rden;
                    }
                    wv[jj] = f2bf(wt);
                }
                *(short8*)(row + j0) = *(const short8*)wv;
            }
        }
    }
    __syncthreads();
    int w = tid >> 6, lane = tid & 63;
    int q = lane >> 4, col = lane & 15;
    const unsigned short* Hb = h2t + (size_t)b * 8192;
    floatx4 acc[4][2];
    #pragma unroll
    for (int mi = 0; mi < 4; mi++)
        #pragma unroll
        for (int ni = 0; ni < 2; ni++)
            acc[mi][ni] = (floatx4){0.f, 0.f, 0.f, 0.f};
    for (int k0 = 0; k0 < 256; k0 += 32) {
        short8 af[4], bf[2];
        #pragma unroll
        for (int mi = 0; mi < 4; mi++)
            af[mi] = *(const short8*)&Ps[((w * 4 + mi) * 16 + col) * PSTR + k0 + q * 8];
        #pragma unroll
        for (int ni = 0; ni < 2; ni++)
            bf[ni] = *(const short8*)(Hb + (size_t)(ni * 16 + col) * 256 + k0 + q * 8);
        #pragma unroll
        for (int mi = 0; mi < 4; mi++)
            #pragma unroll
            for (int ni = 0; ni < 2; ni++)
                acc[mi][ni] = __builtin_amdgcn_mfma_f32_16x16x32_bf16(af[mi], bf[ni], acc[mi][ni], 0, 0, 0);
    }
    __syncthreads();   // all Ps reads complete; reuse as float g-buffer
    float* gf = (float*)Ps;   // [256][33]
    #pragma unroll
    for (int mi = 0; mi < 4; mi++)
        #pragma unroll
        for (int ni = 0; ni < 2; ni++)
            #pragma unroll
            for (int rr = 0; rr < 4; rr++) {
                int i = (w * 4 + mi) * 16 + q * 4 + rr;
                int f = ni * 16 + col;
                gf[i * 33 + f] = acc[mi][ni][rr] + bias2[f];
            }
    __syncthreads();
    // mean-pool (exact k_fc order: i ascending)
    if (tid < 32) {
        int f = tid;
        float s = 0.f;
        for (int i = 0; i < NNODE; i++) s += gf[i * 33 + f];
        s *= (1.0f / 250.0f);
        es2[f] = s;
        dout[16 + b * 32 + f] = s;
    }
    __syncthreads();
    float inv = rsqrtf(1.0f + 1e-5f);
    if (tid < 128) {
        int j = tid;
        float a = fc1b[j];
        #pragma unroll
        for (int k = 0; k < 32; k++) a = fmaf(es2[k], fc1w[k * 128 + j], a);
        a = a * (bnfg[j] * inv) + bnfb[j];
        zs2[j] = fmaxf(a, 0.f);
    }
    __syncthreads();
    if (tid < 2) {
        int o = tid;
        float a = fc2b[o];
        for (int k = 0; k < 128; k++) a = fmaf(zs2[k], fc2w[k * 2 + o], a);
        dout[b * 2 + o] = a;
    }
}

// ---------------- launch ----------------
extern "C" void kernel_launch(void* const* d_in, const int* in_sizes, int n_in,
                              void* d_out, int out_size, void* d_ws, size_t ws_size,
                              hipStream_t stream) {
    (void)in_sizes; (void)n_in; (void)out_size; (void)ws_size;
    const float* x       = (const float*)d_in[0];
    const float* sinc_w  = (const float*)d_in[1];
    const float* conv1_w = (const float*)d_in[2];
    const float* conv1_b = (const float*)d_in[3];
    const float* bn1_g   = (const float*)d_in[4];
    const float* bn1_b   = (const float*)d_in[5];
    const float* conv2_w = (const float*)d_in[6];
    const float* conv2_b = (const float*)d_in[7];
    const float* bn2_g   = (const float*)d_in[8];
    const float* bn2_b   = (const float*)d_in[9];
    const float* gat1_W  = (const float*)d_in[10];
    const float* gat1_as = (const float*)d_in[11];
    const float* gat1_ad = (const float*)d_in[12];
    const float* gat1_bi = (const float*)d_in[13];
    const float* gat2_W  = (const float*)d_in[14];
    const float* gat2_as = (const float*)d_in[15];
    const float* gat2_ad = (const float*)d_in[16];
    const float* gat2_bi = (const float*)d_in[17];
    const float* fc1_w   = (const float*)d_in[18];
    const float* fc1_b   = (const float*)d_in[19];
    const float* bnf_g   = (const float*)d_in[20];
    const float* bnf_b   = (const float*)d_in[21];
    const float* fc2_w   = (const float*)d_in[22];
    const float* fc2_b   = (const float*)d_in[23];
    float* dout = (float*)d_out;

    unsigned short* fh  = (unsigned short*)d_ws;               // 2048*256
    unsigned short* fl  = fh + (size_t)GROWS * 256;
    unsigned short* bch = fl + (size_t)GROWS * 256;            // 576*256 x4
    unsigned short* bcl = bch + (size_t)NBPAD * 256;
    unsigned short* bsh = bcl + (size_t)NBPAD * 256;
    unsigned short* bsl = bsh + (size_t)NBPAD * 256;
    float* GTR = (float*)(bsl + (size_t)NBPAD * 256);          // [576][2048] f32
    float* GTI = GTR + (size_t)GROWS * NBPAD;                  // [576][2048] f32
    float* S0  = GTI + (size_t)GROWS * NBPAD;                  // (dead, layout kept)
    unsigned short* wbt = (unsigned short*)(S0 + 1030104);     // 32*1056
    unsigned short* bpk = wbt + 32 * 1056;                     // 9216
    unsigned short* Bc1 = bpk + 9216;                          // 1024
    unsigned short* Wt  = Bc1 + 1024;                          // 512*KPAD
    unsigned short* nodesb = Wt + (size_t)512 * KPAD;          // 2000*KPAD
    unsigned short* Pn  = nodesb + (size_t)2000 * KPAD;        // (unused, kept for layout)
    unsigned short* h1t = Pn + (size_t)64 * 256 * 256;         // 64*64*256
    unsigned short* h2t = h1t + (size_t)64 * 64 * 256;         // 8*32*256
    unsigned short* P2n = h2t + (size_t)8 * 32 * 256;          // (unused, kept for layout)
    float* hpart = (float*)(P2n + (size_t)8 * 256 * 256);      // 4*1,024,000
    float* ssrc1 = hpart + 4 * 1024000;                        // 16000
    float* sdst1 = ssrc1 + 16000;                              // 16000
    float* g1    = sdst1 + 16000;                              // 1,024,000
    float* s2src = g1 + 1024000;                               // 2000
    float* s2dst = s2src + 2000;                               // 2000

    hipLaunchKernelGGL(k_prep, dim3(3512), dim3(256), 0, stream,
                       x, sinc_w, conv2_w, bn2_g, conv1_w, bn1_g, gat1_W,
                       fh, fl, bch, bcl, bsh, bsl, wbt, bpk, Bc1, Wt, nodesb, h1t, h2t);
    hipLaunchKernelGGL(k_dftsinc, dim3(608), dim3(256), 0, stream,
                       fh, fl, bch, bcl, bsh, bsl, GTR, GTI, x, wbt, nodesb);
    hipLaunchKernelGGL(k_conv2f, dim3(16, 32, 8), dim3(256), 0, stream,
                       GTR, GTI, Bc1, conv1_b, bn1_g, bn1_b, bpk, conv2_b, bn2_g, bn2_b, nodesb);
    hipLaunchKernelGGL(k_gat1s, dim3(8, 32, 4), dim3(256), 0, stream, nodesb, Wt, hpart);
    hipLaunchKernelGGL(k_hred, dim3(2000), dim3(256), 0, stream,
                       hpart, gat1_as, gat1_ad, h1t, ssrc1, sdst1);
    hipLaunchKernelGGL(k_att1, dim3(2, 64), dim3(256), 0, stream,
                       ssrc1, sdst1, h1t, gat1_bi, g1);
    hipLaunchKernelGGL(k_h2, dim3(500), dim3(256), 0, stream,
                       g1, gat2_W, gat2_as, gat2_ad, h2t, s2src, s2dst);
    hipLaunchKernelGGL(k_att2, dim3(8), dim3(256), 0, stream,
                       s2src, s2dst, h2t, gat2_bi,
                       fc1_w, fc1_b, bnf_g, bnf_b, fc2_w, fc2_b, dout);
}

// Round 14
// 287.683 us; speedup vs baseline: 1.0467x; 1.0130x over previous
//
#include <hip/hip_runtime.h>
#include <hip/hip_bf16.h>
#include <math.h>

// ---------------- constants ----------------
#define TB 8
#define TT 64000
#define NFRAMES 251
#define NROWS (TB*NFRAMES)      // 2008
#define GROWS 2048              // 8 * 256 radix-4 sub-rows
#define NBINS 513
#define NBPAD 576
#define NNODE 250
#define NODE_DIM 4116
#define KPAD 4128

typedef __attribute__((ext_vector_type(8))) short short8;
typedef __attribute__((ext_vector_type(4))) float floatx4;

static __device__ __forceinline__ unsigned short f2bf(float x) {
    __hip_bfloat16 h = __float2bfloat16(x);
    return *(unsigned short*)&h;
}
static __device__ __forceinline__ float bf2f(unsigned short u) {
    __hip_bfloat16 h = *(__hip_bfloat16*)&u;
    return __bfloat162float(h);
}

// ---------------- merged prep kernel: all input-only transforms in ONE launch ----------------
__global__ __launch_bounds__(256) void k_prep(
    const float* __restrict__ x, const float* __restrict__ sinc_w,
    const float* __restrict__ c2w, const float* __restrict__ g2bn,
    const float* __restrict__ c1w, const float* __restrict__ g1bn,
    const float* __restrict__ W,
    unsigned short* __restrict__ fh, unsigned short* __restrict__ fl,
    unsigned short* __restrict__ bch, unsigned short* __restrict__ bcl,
    unsigned short* __restrict__ bsh, unsigned short* __restrict__ bsl,
    unsigned short* __restrict__ wbt, unsigned short* __restrict__ Bp,
    unsigned short* __restrict__ Bc1,
    unsigned short* __restrict__ Wt, unsigned short* __restrict__ nodesb,
    unsigned short* __restrict__ h1t, unsigned short* __restrict__ h2t) {
    __shared__ unsigned short tile[64][65];
    int bi = blockIdx.x, tid = threadIdx.x;
    if (bi < 2048) {
        int idx = bi * 256 + tid;
        int row = idx >> 8, r = idx & 255;
        int b = row >> 8, j = row & 255;
        int u = j * 256 + r - 512;
        if (u < 0) u = -u;
        if (u >= TT) u = 2 * TT - 2 - u;
        float v = x[b * TT + u];
        unsigned short h = f2bf(v);
        fh[idx] = h;
        fl[idx] = f2bf(v - bf2f(h));
    } else if (bi < 2624) {
        int idx = (bi - 2048) * 256 + tid;
        int k = idx >> 8, r = idx & 255;
        float s = 0.f, c = 0.f;
        if (k < NBINS) {
            int mm = (k * r) & 1023;
            sincospif((float)mm * (1.0f / 512.0f), &s, &c);
        }
        unsigned short chv = f2bf(c), shv = f2bf(s);
        bch[idx] = chv; bcl[idx] = f2bf(c - bf2f(chv));
        bsh[idx] = shv; bsl[idx] = f2bf(s - bf2f(shv));
    } else if (bi < 3144) {
        int local = bi - 2624;
        int kt = local % 65, nt = local / 65;
        for (int idx = tid; idx < 4096; idx += 256) {
            int r = idx >> 6, c = idx & 63;
            int kp = kt * 64 + r;
            int k;
            if (kp < 20) k = kp;
            else if (kp < NODE_DIM) { int t = kp - 20; k = 20 + (t & 15) * 256 + (t >> 4); }
            else k = -1;
            float v = (k >= 0) ? W[k * 512 + nt * 64 + c] : 0.f;
            tile[r][c] = f2bf(v);
        }
        __syncthreads();
        for (int idx = tid; idx < 4096; idx += 256) {
            int nl = idx >> 6, kl = idx & 63;
            int k = kt * 64 + kl;
            if (k < KPAD)
                Wt[(size_t)(nt * 64 + nl) * KPAD + k] = tile[kl][nl];
        }
    } else if (bi < 3276) {
        int idx = (bi - 3144) * 256 + tid;
        if (idx < 32 * 1056) {
            int c = idx / 1056, m = idx - c * 1056;
            float s = 0.f;
            if (c < 20 && m < 1027) {
                #pragma unroll
                for (int d = 0; d < 4; d++) {
                    int k = m - d;
                    if (k >= 0 && k < 1024) s += sinc_w[c * 1024 + k];
                }
                s *= 0.25f;
            }
            wbt[idx] = f2bf(s);
        }
    } else if (bi < 3312) {
        int idx = (bi - 3276) * 256 + tid;
        if (idx < 9216) {
            int j = idx & 7, lane = (idx >> 3) & 63, ct = (idx >> 9) & 1, s = idx >> 10;
            int co = ct * 16 + (lane & 15);
            int ci = (lane >> 4) * 8 + j;
            float inv = rsqrtf(1.0f + 1e-5f);
            Bp[idx] = f2bf(c2w[co * 288 + ci * 9 + s] * (g2bn[co] * inv));
        }
    } else if (bi < 3508) {
        int idx = (bi - 3312) * 256 + tid;
        if (idx < 24000) {
            int row = idx / 12, c = idx - row * 12;
            nodesb[(size_t)row * KPAD + 4116 + c] = 0;
        } else if (idx < 48576) {
            int t = idx - 24000; int r = t / 6, c = t - r * 6;
            h1t[(size_t)r * 256 + 250 + c] = 0;
        } else if (idx < 50112) {
            int t = idx - 48576; int r = t / 6, c = t - r * 6;
            h2t[(size_t)r * 256 + 250 + c] = 0;
        }
    } else {
        // conv1 weight B-fragments: Bc1[ch=32][k=32], hi/lo 3-term layout
        int idx = (bi - 3508) * 256 + tid;
        if (idx < 1024) {
            int ch = idx >> 5, k = idx & 31;
            float inv = rsqrtf(1.0f + 1e-5f);
            int t; int typ; // 0=hi 1=lo 2=zero
            if (k < 8)       { t = k;      typ = 0; }
            else if (k < 16) { t = k - 8;  typ = 0; }
            else if (k < 24) { t = k - 16; typ = 1; }
            else if (k == 24 || k == 25) { t = 8; typ = 0; }
            else if (k == 26) { t = 8; typ = 1; }
            else { t = 0; typ = 2; }
            unsigned short outv = 0;
            if (typ != 2) {
                float wv = c1w[ch * 9 + t] * (g1bn[ch] * inv);
                unsigned short whi = f2bf(wv);
                outv = (typ == 0) ? whi : f2bf(wv - bf2f(whi));
            }
            Bc1[idx] = outv;
        }
    }
}

// ---------------- radix-4 DFT GEMM (transposed GT[bin][row] output) + sinc conv, one launch ----------------
__global__ __launch_bounds__(256) void k_dftsinc(const unsigned short* __restrict__ fh,
                                                 const unsigned short* __restrict__ fl,
                                                 const unsigned short* __restrict__ ch,
                                                 const unsigned short* __restrict__ cl,
                                                 const unsigned short* __restrict__ sh,
                                                 const unsigned short* __restrict__ sl,
                                                 float* __restrict__ GTR,
                                                 float* __restrict__ GTI,
                                                 const float* __restrict__ x,
                                                 const unsigned short* __restrict__ wbt,
                                                 unsigned short* __restrict__ nodesb) {
    __shared__ __align__(16) unsigned char smem[34048];
    int tid = threadIdx.x;
    int bi = blockIdx.x;
    if (bi >= 576) {
        // ---- sinc conv as MFMA GEMM, M-split ----
        unsigned short* xs = (unsigned short*)smem;   // 1312 ush
        int local = bi - 576;
        int ut = local & 3, b = local >> 2;
        int base = 256 * ut - 512;
        for (int i = tid; i < 1312; i += 256) {
            int g = base + i;
            float v = (g >= 0 && g < TT) ? x[b * TT + g] : 0.f;
            xs[i] = f2bf(v);
        }
        __syncthreads();
        int w = tid >> 6, lane = tid & 63;
        int q = lane >> 4, col = lane & 15;
        floatx4 acc[2];
        acc[0] = acc[1] = (floatx4){0.f, 0.f, 0.f, 0.f};
        for (int K0 = 0; K0 < 1056; K0 += 32) {
            int off = 4 * (w * 16 + col) + K0 + q * 8;
            unsigned long long lo = *(const unsigned long long*)&xs[off];
            unsigned long long hi = *(const unsigned long long*)&xs[off + 4];
            union { unsigned long long u64[2]; short8 s8; } cv;
            cv.u64[0] = lo; cv.u64[1] = hi;
            short8 af = cv.s8;
            #pragma unroll
            for (int ni = 0; ni < 2; ni++) {
                short8 bf = *(const short8*)(wbt + (size_t)(ni * 16 + col) * 1056 + K0 + q * 8);
                acc[ni] = __builtin_amdgcn_mfma_f32_16x16x32_bf16(af, bf, acc[ni], 0, 0, 0);
            }
        }
        #pragma unroll
        for (int ni = 0; ni < 2; ni++)
            #pragma unroll
            for (int rr = 0; rr < 4; rr++) {
                int u = ut * 64 + w * 16 + q * 4 + rr;
                int c = ni * 16 + col;
                if (u < NNODE && c < 20)
                    nodesb[(size_t)(b * NNODE + u) * KPAD + c] = f2bf(acc[ni][rr]);
            }
        return;
    }
    // ---- DFT part ----
    unsigned short* Ah  = (unsigned short*)smem;             // 2560 B
    unsigned short* Al  = (unsigned short*)(smem + 2560);    // 2560 B
    unsigned short* Bch = (unsigned short*)(smem + 5120);    // 5120 B
    unsigned short* Bcl = (unsigned short*)(smem + 10240);
    unsigned short* Bsh = (unsigned short*)(smem + 15360);
    unsigned short* Bsl = (unsigned short*)(smem + 20480);
    float* TR = (float*)(smem + 25600);                      // 64*33*4 = 8448 B
    int N0 = (bi % 9) * 64, M0 = (bi / 9) * 32;
    int br = tid >> 2, bc = (tid & 3) * 8;
    size_t boff = (size_t)(N0 + br) * 256 + bc;
    int ar = (tid & 127) >> 2, ac = (tid & 3) * 8;
    size_t aoff = (size_t)(M0 + ar) * 256 + ac;
    bool loA = tid < 128;
    int w = tid >> 6, lane = tid & 63;
    int q = lane >> 4, col = lane & 15;
    int mb = (w >> 1) * 16, nb = (w & 1) * 32;
    floatx4 aR[2], aI[2];
    aR[0] = aR[1] = aI[0] = aI[1] = (floatx4){0.f, 0.f, 0.f, 0.f};

    for (int K0 = 0; K0 < 256; K0 += 32) {
        if (loA) *(short8*)&Ah[ar * 40 + ac] = *(const short8*)(fh + aoff + K0);
        else     *(short8*)&Al[ar * 40 + ac] = *(const short8*)(fl + aoff + K0);
        *(short8*)&Bch[br * 40 + bc] = *(const short8*)(ch + boff + K0);
        *(short8*)&Bcl[br * 40 + bc] = *(const short8*)(cl + boff + K0);
        *(short8*)&Bsh[br * 40 + bc] = *(const short8*)(sh + boff + K0);
        *(short8*)&Bsl[br * 40 + bc] = *(const short8*)(sl + boff + K0);
        __syncthreads();
        short8 ahv = *(const short8*)&Ah[(mb + col) * 40 + q * 8];
        short8 alv = *(const short8*)&Al[(mb + col) * 40 + q * 8];
        #pragma unroll
        for (int ni = 0; ni < 2; ni++) {
            short8 chv = *(const short8*)&Bch[(nb + ni * 16 + col) * 40 + q * 8];
            short8 clv = *(const short8*)&Bcl[(nb + ni * 16 + col) * 40 + q * 8];
            short8 shv = *(const short8*)&Bsh[(nb + ni * 16 + col) * 40 + q * 8];
            short8 slv = *(const short8*)&Bsl[(nb + ni * 16 + col) * 40 + q * 8];
            aR[ni] = __builtin_amdgcn_mfma_f32_16x16x32_bf16(ahv, chv, aR[ni], 0, 0, 0);
            aR[ni] = __builtin_amdgcn_mfma_f32_16x16x32_bf16(ahv, clv, aR[ni], 0, 0, 0);
            aR[ni] = __builtin_amdgcn_mfma_f32_16x16x32_bf16(alv, chv, aR[ni], 0, 0, 0);
            aI[ni] = __builtin_amdgcn_mfma_f32_16x16x32_bf16(ahv, shv, aI[ni], 0, 0, 0);
            aI[ni] = __builtin_amdgcn_mfma_f32_16x16x32_bf16(ahv, slv, aI[ni], 0, 0, 0);
            aI[ni] = __builtin_amdgcn_mfma_f32_16x16x32_bf16(alv, shv, aI[ni], 0, 0, 0);
        }
        __syncthreads();
    }
    // transpose epilogue via LDS: coalesced GT[bin][row] writes
    int bin_l = tid >> 2, ms = (tid & 3) * 8;
    #pragma unroll
    for (int ni = 0; ni < 2; ni++)
        #pragma unroll
        for (int rr = 0; rr < 4; rr++)
            TR[(nb + ni * 16 + col) * 33 + mb + q * 4 + rr] = aR[ni][rr];
    __syncthreads();
    {
        float* dst = GTR + (size_t)(N0 + bin_l) * 2048 + M0 + ms;
        #pragma unroll
        for (int j = 0; j < 8; j++) dst[j] = TR[bin_l * 33 + ms + j];
    }
    __syncthreads();
    #pragma unroll
    for (int ni = 0; ni < 2; ni++)
        #pragma unroll
        for (int rr = 0; rr < 4; rr++)
            TR[(nb + ni * 16 + col) * 33 + mb + q * 4 + rr] = aI[ni][rr];
    __syncthreads();
    {
        float* dst = GTI + (size_t)(N0 + bin_l) * 2048 + M0 + ms;
        #pragma unroll
        for (int j = 0; j < 8; j++) dst[j] = TR[bin_l * 33 + ms + j];
    }
}

// ---------------- fused conv1+conv2; S0 tile computed inline from GT ----------------
#define O1STR 40
__global__ __launch_bounds__(256) void k_conv2f(const float* __restrict__ GTR,
                                                const float* __restrict__ GTI,
                                                const unsigned short* __restrict__ Bc1,
                                                const float* __restrict__ c1b,
                                                const float* __restrict__ g1bn,
                                                const float* __restrict__ b1bn,
                                                const unsigned short* __restrict__ Bp,
                                                const float* __restrict__ c2b,
                                                const float* __restrict__ g2bn,
                                                const float* __restrict__ b2bn,
                                                unsigned short* __restrict__ nodesb) {
    __shared__ __align__(16) unsigned short o1s[18 * 18 * O1STR];  // 25920 B
    __shared__ float S0s[20][20];
    __shared__ float b1s[32];
    __shared__ float b2s[32];
    int tid = threadIdx.x;
    int b = blockIdx.z;
    int F0 = blockIdx.y * 8;
    int T0 = blockIdx.x * 8;
    float inv = rsqrtf(1.0f + 1e-5f);
    if (tid < 32) {
        b1s[tid] = c1b[tid] * (g1bn[tid] * inv) + b1bn[tid];
        b2s[tid] = c2b[tid] * (g2bn[tid] * inv) + b2bn[tid];
    }
    for (int i = tid; i < 400; i += 256) {
        int r = i / 20, c = i - r * 20;
        int bin = 2 * F0 - 2 + r, fr = 2 * T0 - 2 + c;
        float v = 0.f;
        if (bin >= 0 && bin < 513 && fr >= 0 && fr < 251) {
            size_t base = (size_t)bin * 2048 + b * 256 + fr;
            float gr0 = GTR[base], gr1 = GTR[base + 1], gr2 = GTR[base + 2], gr3 = GTR[base + 3];
            float gs0 = GTI[base], gs1 = GTI[base + 1], gs2 = GTI[base + 2], gs3 = GTI[base + 3];
            float fre, fim;
            switch (bin & 3) {
                case 0: fre = gr0 + gr1 + gr2 + gr3; fim = gs0 + gs1 + gs2 + gs3; break;
                case 1: fre = gr0 - gs1 - gr2 + gs3; fim = gs0 + gr1 - gs2 - gr3; break;
                case 2: fre = gr0 - gr1 + gr2 - gr3; fim = gs0 - gs1 + gs2 - gs3; break;
                default: fre = gr0 + gs1 - gr2 - gs3; fim = gs0 - gr1 - gs2 + gr3; break;
            }
            v = logf(sqrtf(fmaf(fre, fre, fim * fim)) + 1e-9f);
        }
        S0s[r][c] = v;
    }
    __syncthreads();

    int lane = tid & 63, w = tid >> 6;
    int q = lane >> 4, col = lane & 15;

    // ---- conv1 as MFMA: positions p = r*18+t (324), channels 32, K=32 packed hi/lo ----
    {
        short8 bfr0 = *(const short8*)(Bc1 + (size_t)col * 32 + q * 8);
        short8 bfr1 = *(const short8*)(Bc1 + (size_t)(16 + col) * 32 + q * 8);
        for (int mt = w; mt < 21; mt += 4) {
            int p = mt * 16 + col;
            int pc = p < 324 ? p : 0;
            int pr = (pc * 228) >> 12;      // pc/18
            int pt = pc - pr * 18;
            float tv[9];
            #pragma unroll
            for (int di = 0; di < 3; di++)
                #pragma unroll
                for (int dj = 0; dj < 3; dj++)
                    tv[di * 3 + dj] = S0s[pr + di][pt + dj];
            unsigned short hu[9], lu[9];
            #pragma unroll
            for (int i = 0; i < 9; i++) {
                hu[i] = f2bf(tv[i]);
                lu[i] = f2bf(tv[i] - bf2f(hu[i]));
            }
            short8 af;
            if (q == 1) {
                af[0] = lu[0]; af[1] = lu[1]; af[2] = lu[2]; af[3] = lu[3];
                af[4] = lu[4]; af[5] = lu[5]; af[6] = lu[6]; af[7] = lu[7];
            } else if (q == 3) {
                af[0] = hu[8]; af[1] = lu[8]; af[2] = hu[8]; af[3] = 0;
                af[4] = 0; af[5] = 0; af[6] = 0; af[7] = 0;
            } else {
                af[0] = hu[0]; af[1] = hu[1]; af[2] = hu[2]; af[3] = hu[3];
                af[4] = hu[4]; af[5] = hu[5]; af[6] = hu[6]; af[7] = hu[7];
            }
            floatx4 c0 = (floatx4){0.f, 0.f, 0.f, 0.f};
            floatx4 c1 = (floatx4){0.f, 0.f, 0.f, 0.f};
            c0 = __builtin_amdgcn_mfma_f32_16x16x32_bf16(af, bfr0, c0, 0, 0, 0);
            c1 = __builtin_amdgcn_mfma_f32_16x16x32_bf16(af, bfr1, c1, 0, 0, 0);
            #pragma unroll
            for (int rr2 = 0; rr2 < 4; rr2++) {
                int pp = mt * 16 + q * 4 + rr2;
                if (pp < 324) {
                    int qr = (pp * 228) >> 12, qt = pp - qr * 18;
                    int r1 = 2 * F0 - 1 + qr, t1 = 2 * T0 - 1 + qt;
                    bool valid = (r1 >= 0 && r1 < 513 && t1 >= 0 && t1 < 251);
                    float v0 = fmaxf(c0[rr2] + b1s[col], 0.f);
                    float v1 = fmaxf(c1[rr2] + b1s[16 + col], 0.f);
                    o1s[pp * O1STR + col]      = valid ? f2bf(v0) : (unsigned short)0;
                    o1s[pp * O1STR + 16 + col] = valid ? f2bf(v1) : (unsigned short)0;
                }
            }
        }
    }
    __syncthreads();

    floatx4 acc[4][2];
    #pragma unroll
    for (int rt = 0; rt < 4; rt++)
        #pragma unroll
        for (int ct = 0; ct < 2; ct++)
            acc[rt][ct] = (floatx4){0.f, 0.f, 0.f, 0.f};

    #pragma unroll
    for (int s = 0; s < 9; s++) {
        const int di = s / 3, dj = s % 3;
        short8 bf0 = *(const short8*)&Bp[(s * 2 + 0) * 512 + lane * 8];
        short8 bf1 = *(const short8*)&Bp[(s * 2 + 1) * 512 + lane * 8];
        #pragma unroll
        for (int rt = 0; rt < 4; rt++) {
            short8 af = *(const short8*)&o1s[((w * 4 + rt + di) * 18 + (col + dj)) * O1STR + q * 8];
            acc[rt][0] = __builtin_amdgcn_mfma_f32_16x16x32_bf16(af, bf0, acc[rt][0], 0, 0, 0);
            acc[rt][1] = __builtin_amdgcn_mfma_f32_16x16x32_bf16(af, bf1, acc[rt][1], 0, 0, 0);
        }
    }
    __syncthreads();

    unsigned short* nb = o1s;
    #pragma unroll
    for (int ct = 0; ct < 2; ct++) {
        float bb = b2s[ct * 16 + col];
        #pragma unroll
        for (int fp2 = 0; fp2 < 2; fp2++)
            #pragma unroll
            for (int tc2 = 0; tc2 < 2; tc2++) {
                float m0 = fmaxf(
                    fmaxf(acc[2 * fp2][ct][2 * tc2], acc[2 * fp2][ct][2 * tc2 + 1]),
                    fmaxf(acc[2 * fp2 + 1][ct][2 * tc2], acc[2 * fp2 + 1][ct][2 * tc2 + 1]));
                float v = fmaxf(m0 + bb, 0.f);
                int nl = (2 * q + tc2) * 2 + ct;   // 0..15
                int fl = 2 * w + fp2;              // 0..7
                nb[nl * 136 + fl * 16 + col] = f2bf(v);
            }
    }
    __syncthreads();

    int nl = tid >> 4, part = tid & 15;
    int node_g = 2 * T0 + nl;
    if (node_g < NNODE) {
        unsigned short* dst = nodesb + (size_t)(b * NNODE + node_g) * KPAD + 20 + F0 * 16 + part * 8;
        *(short8*)(dst) = *(const short8*)&nb[nl * 136 + part * 8];
    }
}

// ---------------- GAT1 GEMM split-K (bf16 MFMA), BM=128 x BN=64 tile: hpart[kc][2000][512] ----------------
__global__ __launch_bounds__(256) void k_gat1s(const unsigned short* __restrict__ A,
                                               const unsigned short* __restrict__ Bt,
                                               float* __restrict__ hpart) {
    __shared__ __align__(16) unsigned short As[128 * 40];   // 10240 B
    __shared__ __align__(16) unsigned short Bs[64 * 40];    // 5120 B
    int tid = threadIdx.x;
    int N0 = blockIdx.x * 64, M0 = blockIdx.y * 128;
    int kc = blockIdx.z;
    int ks = (kc == 0) ? 0 : (33 + 32 * (kc - 1));
    int ke = 33 + 32 * kc;
    if (kc == 0) ke = 33;
    int sra = tid >> 1, sca = (tid & 1) * 16;    // A: 128 rows x 32 cols, 16 ush/thread
    int srb = tid >> 2, scb = (tid & 3) * 8;     // B: 64 rows x 32 cols, 8 ush/thread
    int w = tid >> 6, lane = tid & 63;
    int q = lane >> 4, col = lane & 15;
    floatx4 acc[2][4];
    #pragma unroll
    for (int mi = 0; mi < 2; mi++)
        #pragma unroll
        for (int ni = 0; ni < 4; ni++)
            acc[mi][ni] = (floatx4){0.f, 0.f, 0.f, 0.f};
    short8 z8 = {0, 0, 0, 0, 0, 0, 0, 0};
    int mA = M0 + sra;
    bool mv = mA < 2000;
    const unsigned short* pa = A + (size_t)mA * KPAD + sca;
    const unsigned short* pb = Bt + (size_t)(N0 + srb) * KPAD + scb;

    for (int kk = ks; kk < ke; kk++) {
        int K0 = kk * 32;
        short8 va0 = mv ? *(const short8*)(pa + K0) : z8;
        short8 va1 = mv ? *(const short8*)(pa + K0 + 8) : z8;
        short8 vb = *(const short8*)(pb + K0);
        *(short8*)&As[sra * 40 + sca]     = va0;
        *(short8*)&As[sra * 40 + sca + 8] = va1;
        *(short8*)&Bs[srb * 40 + scb]     = vb;
        __syncthreads();
        short8 a0 = *(const short8*)&As[(w * 32 + col) * 40 + q * 8];
        short8 a1 = *(const short8*)&As[(w * 32 + 16 + col) * 40 + q * 8];
        short8 b0 = *(const short8*)&Bs[(col) * 40 + q * 8];
        short8 b1 = *(const short8*)&Bs[(16 + col) * 40 + q * 8];
        short8 b2 = *(const short8*)&Bs[(32 + col) * 40 + q * 8];
        short8 b3 = *(const short8*)&Bs[(48 + col) * 40 + q * 8];
        acc[0][0] = __builtin_amdgcn_mfma_f32_16x16x32_bf16(a0, b0, acc[0][0], 0, 0, 0);
        acc[0][1] = __builtin_amdgcn_mfma_f32_16x16x32_bf16(a0, b1, acc[0][1], 0, 0, 0);
        acc[0][2] = __builtin_amdgcn_mfma_f32_16x16x32_bf16(a0, b2, acc[0][2], 0, 0, 0);
        acc[0][3] = __builtin_amdgcn_mfma_f32_16x16x32_bf16(a0, b3, acc[0][3], 0, 0, 0);
        acc[1][0] = __builtin_amdgcn_mfma_f32_16x16x32_bf16(a1, b0, acc[1][0], 0, 0, 0);
        acc[1][1] = __builtin_amdgcn_mfma_f32_16x16x32_bf16(a1, b1, acc[1][1], 0, 0, 0);
        acc[1][2] = __builtin_amdgcn_mfma_f32_16x16x32_bf16(a1, b2, acc[1][2], 0, 0, 0);
        acc[1][3] = __builtin_amdgcn_mfma_f32_16x16x32_bf16(a1, b3, acc[1][3], 0, 0, 0);
        __syncthreads();
    }
    float* out = hpart + (size_t)kc * 1024000;
    #pragma unroll
    for (int mi = 0; mi < 2; mi++)
        #pragma unroll
        for (int ni = 0; ni < 4; ni++)
            #pragma unroll
            for (int rr = 0; rr < 4; rr++) {
                int m = M0 + w * 32 + mi * 16 + q * 4 + rr;
                if (m < 2000)
                    out[m * 512 + N0 + ni * 16 + col] = acc[mi][ni][rr];
            }
}

// reduce 4 partials -> h1t bf16 [bh][f][256], fused GAT1 src/dst scores
__global__ __launch_bounds__(256) void k_hred(const float* __restrict__ hpart,
                                              const float* __restrict__ asrc,
                                              const float* __restrict__ adst,
                                              unsigned short* __restrict__ h1t,
                                              float* __restrict__ ssrc,
                                              float* __restrict__ sdst) {
    int m = blockIdx.x;            // 0..1999
    int tid = threadIdx.x;
    int n1 = tid, n2 = tid + 256;
    size_t base = (size_t)m * 512;
    float s1 = hpart[base + n1] + hpart[base + n1 + 1024000] +
               hpart[base + n1 + 2048000] + hpart[base + n1 + 3072000];
    float s2 = hpart[base + n2] + hpart[base + n2 + 1024000] +
               hpart[base + n2 + 2048000] + hpart[base + n2 + 3072000];
    int bb = m / NNODE, j = m - bb * NNODE;
    int hh1 = n1 >> 6, f1 = n1 & 63;
    int hh2 = n2 >> 6, f2 = n2 & 63;
    h1t[((size_t)((bb * 8 + hh1) * 64 + f1)) * 256 + j] = f2bf(s1);
    h1t[((size_t)((bb * 8 + hh2) * 64 + f2)) * 256 + j] = f2bf(s2);
    float ps1 = s1 * asrc[n1], pd1 = s1 * adst[n1];
    float ps2 = s2 * asrc[n2], pd2 = s2 * adst[n2];
    for (int off = 32; off > 0; off >>= 1) {
        ps1 += __shfl_down(ps1, off); pd1 += __shfl_down(pd1, off);
        ps2 += __shfl_down(ps2, off); pd2 += __shfl_down(pd2, off);
    }
    int lane = tid & 63, w = tid >> 6;
    if (lane == 0) {
        ssrc[m * 8 + w] = ps1;     sdst[m * 8 + w] = pd1;
        ssrc[m * 8 + 4 + w] = ps2; sdst[m * 8 + 4 + w] = pd2;
    }
}

// ---------------- fused GAT1 attention: weights in LDS + MFMA apply ----------------
#define PSTR 264
__global__ __launch_bounds__(256) void k_att1(const float* __restrict__ ssrc,
                                              const float* __restrict__ sdst,
                                              const unsigned short* __restrict__ h1t,
                                              const float* __restrict__ bias,
                                              float* __restrict__ g1) {
    __shared__ __align__(16) unsigned short Ps[128 * PSTR];   // 67584 B
    __shared__ float ss[NNODE];
    __shared__ float red[4];
    int mhalf = blockIdx.x, bh = blockIdx.y;
    int b = bh >> 3, h = bh & 7;
    int tid = threadIdx.x;
    for (int j = tid; j < NNODE; j += 256) ss[j] = ssrc[(b * NNODE + j) * 8 + h];
    __syncthreads();
    float mv = (tid < NNODE) ? ss[tid] : -1e30f;
    for (int off = 32; off > 0; off >>= 1) mv = fmaxf(mv, __shfl_down(mv, off));
    if ((tid & 63) == 0) red[tid >> 6] = mv;
    __syncthreads();
    float smaxv = fmaxf(fmaxf(red[0], red[1]), fmaxf(red[2], red[3]));
    if (tid < 128) {
        unsigned short* row = Ps + tid * PSTR;
        int row_g = mhalf * 128 + tid;
        short8 z8 = {0, 0, 0, 0, 0, 0, 0, 0};
        if (row_g >= NNODE) {
            #pragma unroll
            for (int j = 0; j < 256; j += 8) *(short8*)(row + j) = z8;
        } else {
            float d = sdst[(b * NNODE + row_g) * 8 + h];
            float e0 = d + smaxv;
            float mx = e0 > 0.f ? e0 : 0.2f * e0;
            float den = 0.f;
            for (int j = 0; j < NNODE; j++) {
                float e = d + ss[j];
                e = e > 0.f ? e : 0.2f * e;
                den += __expf(e - mx);
            }
            float rden = 1.f / den;
            for (int j0 = 0; j0 < 256; j0 += 8) {
                unsigned short wv[8];
                #pragma unroll
                for (int jj = 0; jj < 8; jj++) {
                    int j = j0 + jj;
                    float wt = 0.f;
                    if (j < NNODE) {
                        float e = d + ss[j];
                        e = e > 0.f ? e : 0.2f * e;
                        wt = __expf(e - mx) * rden;
                    }
                    wv[jj] = f2bf(wt);
                }
                *(short8*)(row + j0) = *(const short8*)wv;
            }
        }
    }
    __syncthreads();
    int w = tid >> 6, lane = tid & 63;
    int q = lane >> 4, col = lane & 15;
    const unsigned short* Hb = h1t + (size_t)bh * 16384;
    floatx4 acc[2][4];
    #pragma unroll
    for (int mi = 0; mi < 2; mi++)
        #pragma unroll
        for (int ni = 0; ni < 4; ni++)
            acc[mi][ni] = (floatx4){0.f, 0.f, 0.f, 0.f};
    for (int k0 = 0; k0 < 256; k0 += 32) {
        short8 af[2], bf[4];
        #pragma unroll
        for (int mi = 0; mi < 2; mi++)
            af[mi] = *(const short8*)&Ps[((w * 2 + mi) * 16 + col) * PSTR + k0 + q * 8];
        #pragma unroll
        for (int ni = 0; ni < 4; ni++)
            bf[ni] = *(const short8*)(Hb + (size_t)(ni * 16 + col) * 256 + k0 + q * 8);
        #pragma unroll
        for (int mi = 0; mi < 2; mi++)
            #pragma unroll
            for (int ni = 0; ni < 4; ni++)
                acc[mi][ni] = __builtin_amdgcn_mfma_f32_16x16x32_bf16(af[mi], bf[ni], acc[mi][ni], 0, 0, 0);
    }
    #pragma unroll
    for (int mi = 0; mi < 2; mi++)
        #pragma unroll
        for (int ni = 0; ni < 4; ni++)
            #pragma unroll
            for (int rr = 0; rr < 4; rr++) {
                int i = mhalf * 128 + (w * 2 + mi) * 16 + q * 4 + rr;
                int f = ni * 16 + col;
                if (i < NNODE)
                    g1[(b * NNODE + i) * 512 + h * 64 + f] =
                        fmaxf(acc[mi][ni][rr] + bias[h * 64 + f], 0.f);
            }
}

// ---------------- GAT2 ----------------
__global__ __launch_bounds__(256) void k_h2(const float* __restrict__ g1,
                                            const float* __restrict__ W2,
                                            const float* __restrict__ a2src,
                                            const float* __restrict__ a2dst,
                                            unsigned short* __restrict__ h2t,
                                            float* __restrict__ s2src,
                                            float* __restrict__ s2dst) {
    int row = blockIdx.x * 4 + (threadIdx.x >> 6);
    if (row >= 2000) return;
    int lane = threadIdx.x & 63;
    int o = lane & 31, half = lane >> 5;
    const float* gr = &g1[row * 512 + half * 256];
    float acc = 0.f;
    for (int k = 0; k < 256; k++) acc = fmaf(gr[k], W2[(half * 256 + k) * 32 + o], acc);
    acc += __shfl_down(acc, 32);
    float ps = acc * a2src[o], pd = acc * a2dst[o];
    for (int off = 16; off > 0; off >>= 1) {
        ps += __shfl_down(ps, off, 32);
        pd += __shfl_down(pd, off, 32);
    }
    if (lane == 0) { s2src[row] = ps; s2dst[row] = pd; }
    if (lane < 32) {
        int b = row / NNODE, j = row - b * NNODE;
        h2t[((size_t)(b * 32 + o)) * 256 + j] = f2bf(acc);
    }
}

// ---------------- fused GAT2 attention + mean-pool + FC head ----------------
// grid (8): one block per batch.
__global__ __launch_bounds__(256) void k_att2(const float* __restrict__ s2src,
                                              const float* __restrict__ s2dst,
                                              const unsigned short* __restrict__ h2t,
                                              const float* __restrict__ bias2,
                                              const float* __restrict__ fc1w,
                                              const float* __restrict__ fc1b,
                                              const float* __restrict__ bnfg,
                                              const float* __restrict__ bnfb,
                                              const float* __restrict__ fc2w,
                                              const float* __restrict__ fc2b,
                                              float* __restrict__ dout) {
    __shared__ __align__(16) unsigned short Ps[256 * PSTR];   // 135168 B (reused as f32 g-buffer)
    __shared__ float ss[NNODE];
    __shared__ float red[4];
    __shared__ float es2[32];
    __shared__ float zs2[128];
    int b = blockIdx.x;
    int tid = threadIdx.x;
    for (int j = tid; j < NNODE; j += 256) ss[j] = s2src[b * NNODE + j];
    __syncthreads();
    float mv = (tid < NNODE) ? ss[tid] : -1e30f;
    for (int off = 32; off > 0; off >>= 1) mv = fmaxf(mv, __shfl_down(mv, off));
    if ((tid & 63) == 0) red[tid >> 6] = mv;
    __syncthreads();
    float smaxv = fmaxf(fmaxf(red[0], red[1]), fmaxf(red[2], red[3]));
    {
        unsigned short* row = Ps + tid * PSTR;
        short8 z8 = {0, 0, 0, 0, 0, 0, 0, 0};
        if (tid >= NNODE) {
            #pragma unroll
            for (int j = 0; j < 256; j += 8) *(short8*)(row + j) = z8;
        } else {
            float d = s2dst[b * NNODE + tid];
            float e0 = d + smaxv;
            float mx = e0 > 0.f ? e0 : 0.2f * e0;
            float den = 0.f;
            for (int j = 0; j < NNODE; j++) {
                float e = d + ss[j];
                e = e > 0.f ? e : 0.2f * e;
                den += __expf(e - mx);
            }
            float rden = 1.f / den;
            for (int j0 = 0; j0 < 256; j0 += 8) {
                unsigned short wv[8];
                #pragma unroll
                for (int jj = 0; jj < 8; jj++) {
                    int j = j0 + jj;
                    float wt = 0.f;
                    if (j < NNODE) {
                        float e = d + ss[j];
                        e = e > 0.f ? e : 0.2f * e;
                        wt = __expf(e - mx) * rden;
                    }
                    wv[jj] = f2bf(wt);
                }
                *(short8*)(row + j0) = *(const short8*)wv;
            }
        }
    }
    __syncthreads();
    int w = tid >> 6, lane = tid & 63;
    int q = lane >> 4, col = lane & 15;
    const unsigned short* Hb = h2t + (size_t)b * 8192;
    floatx4 acc[4][2];
    #pragma unroll
    for (int mi = 0; mi < 4; mi++)
        #pragma unroll
        for (int ni = 0; ni < 2; ni++)
            acc[mi][ni] = (floatx4){0.f, 0.f, 0.f, 0.f};
    for (int k0 = 0; k0 < 256; k0 += 32) {
        short8 af[4], bf[2];
        #pragma unroll
        for (int mi = 0; mi < 4; mi++)
            af[mi] = *(const short8*)&Ps[((w * 4 + mi) * 16 + col) * PSTR + k0 + q * 8];
        #pragma unroll
        for (int ni = 0; ni < 2; ni++)
            bf[ni] = *(const short8*)(Hb + (size_t)(ni * 16 + col) * 256 + k0 + q * 8);
        #pragma unroll
        for (int mi = 0; mi < 4; mi++)
            #pragma unroll
            for (int ni = 0; ni < 2; ni++)
                acc[mi][ni] = __builtin_amdgcn_mfma_f32_16x16x32_bf16(af[mi], bf[ni], acc[mi][ni], 0, 0, 0);
    }
    __syncthreads();   // all Ps reads complete; reuse as float g-buffer
    float* gf = (float*)Ps;   // [256][33]
    #pragma unroll
    for (int mi = 0; mi < 4; mi++)
        #pragma unroll
        for (int ni = 0; ni < 2; ni++)
            #pragma unroll
            for (int rr = 0; rr < 4; rr++) {
                int i = (w * 4 + mi) * 16 + q * 4 + rr;
                int f = ni * 16 + col;
                gf[i * 33 + f] = acc[mi][ni][rr] + bias2[f];
            }
    __syncthreads();
    // mean-pool (exact k_fc order: i ascending)
    if (tid < 32) {
        int f = tid;
        float s = 0.f;
        for (int i = 0; i < NNODE; i++) s += gf[i * 33 + f];
        s *= (1.0f / 250.0f);
        es2[f] = s;
        dout[16 + b * 32 + f] = s;
    }
    __syncthreads();
    float inv = rsqrtf(1.0f + 1e-5f);
    if (tid < 128) {
        int j = tid;
        float a = fc1b[j];
        #pragma unroll
        for (int k = 0; k < 32; k++) a = fmaf(es2[k], fc1w[k * 128 + j], a);
        a = a * (bnfg[j] * inv) + bnfb[j];
        zs2[j] = fmaxf(a, 0.f);
    }
    __syncthreads();
    if (tid < 2) {
        int o = tid;
        float a = fc2b[o];
        for (int k = 0; k < 128; k++) a = fmaf(zs2[k], fc2w[k * 2 + o], a);
        dout[b * 2 + o] = a;
    }
}

// ---------------- launch ----------------
extern "C" void kernel_launch(void* const* d_in, const int* in_sizes, int n_in,
                              void* d_out, int out_size, void* d_ws, size_t ws_size,
                              hipStream_t stream) {
    (void)in_sizes; (void)n_in; (void)out_size; (void)ws_size;
    const float* x       = (const float*)d_in[0];
    const float* sinc_w  = (const float*)d_in[1];
    const float* conv1_w = (const float*)d_in[2];
    const float* conv1_b = (const float*)d_in[3];
    const float* bn1_g   = (const float*)d_in[4];
    const float* bn1_b   = (const float*)d_in[5];
    const float* conv2_w = (const float*)d_in[6];
    const float* conv2_b = (const float*)d_in[7];
    const float* bn2_g   = (const float*)d_in[8];
    const float* bn2_b   = (const float*)d_in[9];
    const float* gat1_W  = (const float*)d_in[10];
    const float* gat1_as = (const float*)d_in[11];
    const float* gat1_ad = (const float*)d_in[12];
    const float* gat1_bi = (const float*)d_in[13];
    const float* gat2_W  = (const float*)d_in[14];
    const float* gat2_as = (const float*)d_in[15];
    const float* gat2_ad = (const float*)d_in[16];
    const float* gat2_bi = (const float*)d_in[17];
    const float* fc1_w   = (const float*)d_in[18];
    const float* fc1_b   = (const float*)d_in[19];
    const float* bnf_g   = (const float*)d_in[20];
    const float* bnf_b   = (const float*)d_in[21];
    const float* fc2_w   = (const float*)d_in[22];
    const float* fc2_b   = (const float*)d_in[23];
    float* dout = (float*)d_out;

    unsigned short* fh  = (unsigned short*)d_ws;               // 2048*256
    unsigned short* fl  = fh + (size_t)GROWS * 256;
    unsigned short* bch = fl + (size_t)GROWS * 256;            // 576*256 x4
    unsigned short* bcl = bch + (size_t)NBPAD * 256;
    unsigned short* bsh = bcl + (size_t)NBPAD * 256;
    unsigned short* bsl = bsh + (size_t)NBPAD * 256;
    float* GTR = (float*)(bsl + (size_t)NBPAD * 256);          // [576][2048] f32
    float* GTI = GTR + (size_t)GROWS * NBPAD;                  // [576][2048] f32
    float* S0  = GTI + (size_t)GROWS * NBPAD;                  // (dead, layout kept)
    unsigned short* wbt = (unsigned short*)(S0 + 1030104);     // 32*1056
    unsigned short* bpk = wbt + 32 * 1056;                     // 9216
    unsigned short* Bc1 = bpk + 9216;                          // 1024
    unsigned short* Wt  = Bc1 + 1024;                          // 512*KPAD
    unsigned short* nodesb = Wt + (size_t)512 * KPAD;          // 2000*KPAD
    unsigned short* Pn  = nodesb + (size_t)2000 * KPAD;        // (unused, kept for layout)
    unsigned short* h1t = Pn + (size_t)64 * 256 * 256;         // 64*64*256
    unsigned short* h2t = h1t + (size_t)64 * 64 * 256;         // 8*32*256
    unsigned short* P2n = h2t + (size_t)8 * 32 * 256;          // (unused, kept for layout)
    float* hpart = (float*)(P2n + (size_t)8 * 256 * 256);      // 4*1,024,000
    float* ssrc1 = hpart + 4 * 1024000;                        // 16000
    float* sdst1 = ssrc1 + 16000;                              // 16000
    float* g1    = sdst1 + 16000;                              // 1,024,000
    float* s2src = g1 + 1024000;                               // 2000
    float* s2dst = s2src + 2000;                               // 2000

    hipLaunchKernelGGL(k_prep, dim3(3512), dim3(256), 0, stream,
                       x, sinc_w, conv2_w, bn2_g, conv1_w, bn1_g, gat1_W,
                       fh, fl, bch, bcl, bsh, bsl, wbt, bpk, Bc1, Wt, nodesb, h1t, h2t);
    hipLaunchKernelGGL(k_dftsinc, dim3(608), dim3(256), 0, stream,
                       fh, fl, bch, bcl, bsh, bsl, GTR, GTI, x, wbt, nodesb);
    hipLaunchKernelGGL(k_conv2f, dim3(16, 32, 8), dim3(256), 0, stream,
                       GTR, GTI, Bc1, conv1_b, bn1_g, bn1_b, bpk, conv2_b, bn2_g, bn2_b, nodesb);
    hipLaunchKernelGGL(k_gat1s, dim3(8, 16, 4), dim3(256), 0, stream, nodesb, Wt, hpart);
    hipLaunchKernelGGL(k_hred, dim3(2000), dim3(256), 0, stream,
                       hpart, gat1_as, gat1_ad, h1t, ssrc1, sdst1);
    hipLaunchKernelGGL(k_att1, dim3(2, 64), dim3(256), 0, stream,
                       ssrc1, sdst1, h1t, gat1_bi, g1);
    hipLaunchKernelGGL(k_h2, dim3(500), dim3(256), 0, stream,
                       g1, gat2_W, gat2_as, gat2_ad, h2t, s2src, s2dst);
    hipLaunchKernelGGL(k_att2, dim3(8), dim3(256), 0, stream,
                       s2src, s2dst, h2t, gat2_bi,
                       fc1_w, fc1_b, bnf_g, bnf_b, fc2_w, fc2_b, dout);
}